// Round 14
// baseline (82.922 us; speedup 1.0000x reference)
//
#include <hip/hip_runtime.h>
#include <hip/hip_bf16.h>

// AttentionMixerRec: B=256 S=200 D=256 V=100000 L=5 H=4
// scores[b,h,l,s] = (ql[b,l] @ U[h]) . emb[b,s] / 16
//   U[h] = WQ[h]^T WK[h];  ql[b,l] = qpre[b,l] @ lin[l]^T;
//   qpre[b,l] = sum of emb rows s in [max(len-1-l,0), len-1].
// v14: v13 (52.3us) minus the k_qpre kernel: ql tiles widened to 64b x 256e
//     (4 per l, 20 blocks) so each gathers its qpre slab ONCE (v11's 4x
//     redundancy was the regression cause, not the gather per se). qpre never
//     hits global. 3 kernels / 2 boundaries. k_qt + attn = v13 verbatim.

#define DD 256
#define SS 200
#define BB 256
#define LL 5
#define HH 4
#define NC 20   // H*L
#define P_ER 264   // er pitch in halves
#define P_BF 264   // bf16 slab pitch (2-way bank alias = free)

typedef __attribute__((ext_vector_type(8))) short bf16x8;
typedef __attribute__((ext_vector_type(4))) float f32x4;

__device__ __forceinline__ unsigned short f2bf(float f) {
    __hip_bfloat16 h = __float2bfloat16(f);
    union { __hip_bfloat16 b; unsigned short u; } c; c.b = h; return c.u;
}

// ---- U tile: fp32, K in [ks, ks+128), transposed fp32 epilogue O[j][i] ----
__device__ __forceinline__ void u_tile(const float* __restrict__ A,
                                       const float* __restrict__ B,
                                       float* __restrict__ O,
                                       int tile, int ks, float* lds) {
    float (*As)[68] = (float(*)[68])lds;
    float (*Bs)[68] = (float(*)[68])(lds + 32 * 68);
    int i0 = (tile >> 2) * 64, j0 = (tile & 3) * 64;
    int t = threadIdx.x;
    int tx = t & 15, ty = t >> 4;
    float acc[4][4] = {};
    for (int k0 = ks; k0 < ks + 128; k0 += 32) {
        #pragma unroll
        for (int r = 0; r < 8; ++r) {
            int e = r * 256 + t;
            int kk = e >> 6, ii = e & 63;
            As[kk][ii] = A[(size_t)(k0 + kk) * DD + i0 + ii];
            Bs[kk][ii] = B[(size_t)(k0 + kk) * DD + j0 + ii];
        }
        __syncthreads();
        #pragma unroll
        for (int kk = 0; kk < 32; ++kk) {
            float4 av = *(const float4*)&As[kk][tx * 4];
            float4 bv = *(const float4*)&Bs[kk][ty * 4];
            float a[4] = {av.x, av.y, av.z, av.w};
            float b[4] = {bv.x, bv.y, bv.z, bv.w};
            #pragma unroll
            for (int p = 0; p < 4; ++p)
                #pragma unroll
                for (int q = 0; q < 4; ++q)
                    acc[p][q] += a[p] * b[q];
        }
        __syncthreads();
    }
    #pragma unroll
    for (int q = 0; q < 4; ++q) {
        float4 v = {acc[0][q], acc[1][q], acc[2][q], acc[3][q]};
        *(float4*)&O[(size_t)(j0 + ty * 4 + q) * DD + i0 + tx * 4] = v;
    }
}

// ---- K1: blocks 0..127 = U K-split tiles; 128..147 = ql (gather + MFMA) ----
__global__ __launch_bounds__(256) void k_wu3(const float* __restrict__ wq,
                                             const float* __restrict__ wk,
                                             const float* __restrict__ lin,
                                             const int* __restrict__ seq,
                                             const int* __restrict__ slen,
                                             const float* __restrict__ emb,
                                             float* __restrict__ Upart,
                                             unsigned short* __restrict__ ql_bf) {
    __shared__ char ldsraw[2 * 64 * P_BF * 2];   // 67.6 KB, shared by both paths
    int blk = blockIdx.x, t = threadIdx.x;

    if (blk < 128) {
        int h = blk >> 5, rem = blk & 31;
        int p = rem >> 4, tile = rem & 15;
        u_tile(wq + (size_t)h * 65536, wk + (size_t)h * 65536,
               Upart + (size_t)(h * 2 + p) * 65536, tile, p * 128, (float*)ldsraw);
        return;
    }

    // ---- ql slab: 64 b x 256 e for level l; gather qpre ONCE, 4 e-chunks ----
    int z = blk - 128;
    int l = z >> 2, slab = z & 3;
    int b0 = slab * 64;
    unsigned short* QP = (unsigned short*)ldsraw;   // [64][P_BF] qpre bf16
    unsigned short* SB = QP + 64 * P_BF;            // [64][P_BF] lin chunk bf16
    int lane = t & 63, w = t >> 6;
    int fr = lane & 15, ko = (lane >> 4) * 8;
    int crow = (lane >> 4) * 4, ccol = lane & 15;

    // gather qpre[b0+r][:] = sum of <=5 emb rows (v11-proven pattern)
    for (int r = w; r < 64; r += 4) {
        int b = b0 + r;
        int len = slen[b];
        int lo = max(len - 1 - l, 0);
        float4 a4 = {0.f, 0.f, 0.f, 0.f};
        for (int s = lo; s < len; ++s) {
            int row = __builtin_amdgcn_readfirstlane(seq[b * SS + s]);
            float4 v = *(const float4*)&emb[(size_t)row * DD + lane * 4];
            a4.x += v.x; a4.y += v.y; a4.z += v.z; a4.w += v.w;
        }
        ushort4 o;
        o.x = f2bf(a4.x); o.y = f2bf(a4.y); o.z = f2bf(a4.z); o.w = f2bf(a4.w);
        *(ushort4*)&QP[r * P_BF + lane * 4] = o;
    }

    for (int ec = 0; ec < 4; ++ec) {
        // stage lin[l][ec*64 + rr][:] fp32 -> bf16 (coalesced full rows)
        for (int rr = w; rr < 64; rr += 4) {
            float4 v = *(const float4*)&lin[(size_t)l * 65536 +
                                            (size_t)(ec * 64 + rr) * DD + lane * 4];
            ushort4 o;
            o.x = f2bf(v.x); o.y = f2bf(v.y); o.z = f2bf(v.z); o.w = f2bf(v.w);
            *(ushort4*)&SB[rr * P_BF + lane * 4] = o;
        }
        __syncthreads();   // first iter also covers QP
        f32x4 accq[4] = {{0.f,0.f,0.f,0.f},{0.f,0.f,0.f,0.f},
                         {0.f,0.f,0.f,0.f},{0.f,0.f,0.f,0.f}};
        for (int kk = 0; kk < 8; ++kk) {
            int kb = kk * 32 + ko;
            bf16x8 a = *(const bf16x8*)&QP[(w * 16 + fr) * P_BF + kb];
            #pragma unroll
            for (int n = 0; n < 4; ++n) {
                bf16x8 bq = *(const bf16x8*)&SB[(n * 16 + fr) * P_BF + kb];
                accq[n] = __builtin_amdgcn_mfma_f32_16x16x32_bf16(a, bq, accq[n], 0, 0, 0);
            }
        }
        // D: row=(lane>>4)*4+j, col=lane&15 [proven]
        #pragma unroll
        for (int n = 0; n < 4; ++n)
            #pragma unroll
            for (int j = 0; j < 4; ++j)
                ql_bf[((size_t)l * 256 + b0 + w * 16 + crow + j) * DD
                      + ec * 64 + n * 16 + ccol] = f2bf(accq[n][j]);
        __syncthreads();   // SB safe to restage
    }
}

// ---- k_qt: Qt[z=h*5+l][b][d'] via bf16 MFMA, tile 128x64, 160 blocks ----
// B-staging sums the two U fp32 partials and converts to bf16 (v11-proven).
__global__ __launch_bounds__(256) void k_qt(const unsigned short* __restrict__ ql_bf,
                                            const float* __restrict__ Upart,
                                            float* __restrict__ Qt) {
    __shared__ unsigned short Asl[128 * P_BF];
    __shared__ unsigned short Bsl[64 * P_BF];
    int blk = blockIdx.x;
    int z = blk >> 3, sub = blk & 7;
    int h = z / 5, l = z % 5;
    int b0 = (sub >> 2) * 128, d0 = (sub & 3) * 64;
    int t = threadIdx.x, lane = t & 63, w = t >> 6;

    const unsigned short* gA = ql_bf + ((size_t)l * 256 + b0) * DD;
    #pragma unroll
    for (int r = 0; r < 16; ++r) {
        int c = r * 256 + t;
        int row = c >> 5, kc = c & 31;
        *(uint4*)&Asl[row * P_BF + kc * 8] = *(const uint4*)&gA[(size_t)row * DD + kc * 8];
    }
    const float* gB0 = Upart + (size_t)(h * 2 + 0) * 65536 + (size_t)d0 * DD;
    const float* gB1 = Upart + (size_t)(h * 2 + 1) * 65536 + (size_t)d0 * DD;
    #pragma unroll
    for (int r = 0; r < 8; ++r) {
        int c = r * 256 + t;
        int row = c >> 5, kc = c & 31;
        float4 u0 = *(const float4*)&gB0[(size_t)row * DD + kc * 8];
        float4 u1 = *(const float4*)&gB0[(size_t)row * DD + kc * 8 + 4];
        float4 v0 = *(const float4*)&gB1[(size_t)row * DD + kc * 8];
        float4 v1 = *(const float4*)&gB1[(size_t)row * DD + kc * 8 + 4];
        ushort4 o0, o1;
        o0.x = f2bf(u0.x + v0.x); o0.y = f2bf(u0.y + v0.y);
        o0.z = f2bf(u0.z + v0.z); o0.w = f2bf(u0.w + v0.w);
        o1.x = f2bf(u1.x + v1.x); o1.y = f2bf(u1.y + v1.y);
        o1.z = f2bf(u1.z + v1.z); o1.w = f2bf(u1.w + v1.w);
        *(ushort4*)&Bsl[row * P_BF + kc * 8] = o0;
        *(ushort4*)&Bsl[row * P_BF + kc * 8 + 4] = o1;
    }
    __syncthreads();

    f32x4 zero = {0.f, 0.f, 0.f, 0.f};
    f32x4 acc[2][4];
    #pragma unroll
    for (int p = 0; p < 2; ++p)
        #pragma unroll
        for (int q = 0; q < 4; ++q) acc[p][q] = zero;

    int ar = w * 32 + (lane & 15);
    int br = lane & 15;
    int ko = (lane >> 4) * 8;
    for (int kk = 0; kk < 8; ++kk) {
        int kb = kk * 32 + ko;
        bf16x8 a0 = *(const bf16x8*)&Asl[(size_t)ar * P_BF + kb];
        bf16x8 a1 = *(const bf16x8*)&Asl[(size_t)(ar + 16) * P_BF + kb];
        bf16x8 b0 = *(const bf16x8*)&Bsl[(size_t)br * P_BF + kb];
        bf16x8 b1 = *(const bf16x8*)&Bsl[(size_t)(br + 16) * P_BF + kb];
        bf16x8 b2 = *(const bf16x8*)&Bsl[(size_t)(br + 32) * P_BF + kb];
        bf16x8 b3 = *(const bf16x8*)&Bsl[(size_t)(br + 48) * P_BF + kb];
        acc[0][0] = __builtin_amdgcn_mfma_f32_16x16x32_bf16(a0, b0, acc[0][0], 0, 0, 0);
        acc[0][1] = __builtin_amdgcn_mfma_f32_16x16x32_bf16(a0, b1, acc[0][1], 0, 0, 0);
        acc[0][2] = __builtin_amdgcn_mfma_f32_16x16x32_bf16(a0, b2, acc[0][2], 0, 0, 0);
        acc[0][3] = __builtin_amdgcn_mfma_f32_16x16x32_bf16(a0, b3, acc[0][3], 0, 0, 0);
        acc[1][0] = __builtin_amdgcn_mfma_f32_16x16x32_bf16(a1, b0, acc[1][0], 0, 0, 0);
        acc[1][1] = __builtin_amdgcn_mfma_f32_16x16x32_bf16(a1, b1, acc[1][1], 0, 0, 0);
        acc[1][2] = __builtin_amdgcn_mfma_f32_16x16x32_bf16(a1, b2, acc[1][2], 0, 0, 0);
        acc[1][3] = __builtin_amdgcn_mfma_f32_16x16x32_bf16(a1, b3, acc[1][3], 0, 0, 0);
    }

    int crow = (lane >> 4) * 4, ccol = lane & 15;
    float* Qb = Qt + (size_t)z * 65536;
    #pragma unroll
    for (int p = 0; p < 2; ++p)
        #pragma unroll
        for (int q = 0; q < 4; ++q)
            #pragma unroll
            for (int j = 0; j < 4; ++j) {
                int row = b0 + w * 32 + p * 16 + crow + j;
                int col = d0 + q * 16 + ccol;
                Qb[(size_t)row * DD + col] = acc[p][q][j];
            }
}

// ---- fused attention (v13 verbatim); phase A = bf16 MFMA ----
__global__ __launch_bounds__(1024, 4) void k_attn_out(const int* __restrict__ seq,
                                                      const float* __restrict__ emb,
                                                      const float* __restrict__ Qt,
                                                      float* __restrict__ out) {
    __shared__ float smem[38016];
    __shared__ float ssum[NC];
    unsigned short* qtb = (unsigned short*)smem;            // [32][P_BF]
    unsigned short* er  = (unsigned short*)(smem + 4224);   // [256][P_ER]
    float* e      = smem + 4224;
    float* pooled = e + NC * 256;
    float* par    = pooled + 256;

    int b = blockIdx.x, t = threadIdx.x;
    int lane = t & 63, wave = t >> 6;

    for (int r = wave; r < 32; r += 16) {
        if (r < NC) {
            float4 v = *(const float4*)&Qt[((size_t)r * BB + b) * DD + lane * 4];
            ushort4 o;
            o.x = f2bf(v.x); o.y = f2bf(v.y); o.z = f2bf(v.z); o.w = f2bf(v.w);
            *(ushort4*)&qtb[r * P_BF + lane * 4] = o;
        } else {
            ushort4 zz = {0, 0, 0, 0};
            *(ushort4*)&qtb[r * P_BF + lane * 4] = zz;
        }
    }
    for (int r = wave; r < 256; r += 16) {
        if (r < SS) {
            int row = __builtin_amdgcn_readfirstlane(seq[b * SS + r]);
            float4 v = *(const float4*)&emb[(size_t)row * DD + lane * 4];
            ushort4 o;
            o.x = f2bf(v.x); o.y = f2bf(v.y); o.z = f2bf(v.z); o.w = f2bf(v.w);
            *(ushort4*)&er[r * P_ER + lane * 4] = o;
        } else {
            ushort4 zz = {0, 0, 0, 0};
            *(ushort4*)&er[r * P_ER + lane * 4] = zz;
        }
    }
    __syncthreads();

    int fr = lane & 15, ko = (lane >> 4) * 8;
    int crow = (lane >> 4) * 4, ccol = lane & 15;
    f32x4 zero4 = {0.f, 0.f, 0.f, 0.f};
    f32x4 acc0 = zero4, acc1 = zero4;
    const unsigned short* erb = er + (wave * 16 + fr) * P_ER;
    #pragma unroll
    for (int kk = 0; kk < 8; ++kk) {
        int kb = kk * 32 + ko;
        bf16x8 bv = *(const bf16x8*)&erb[kb];
        bf16x8 a0 = *(const bf16x8*)&qtb[fr * P_BF + kb];
        bf16x8 a1 = *(const bf16x8*)&qtb[(16 + fr) * P_BF + kb];
        acc0 = __builtin_amdgcn_mfma_f32_16x16x32_bf16(a0, bv, acc0, 0, 0, 0);
        acc1 = __builtin_amdgcn_mfma_f32_16x16x32_bf16(a1, bv, acc1, 0, 0, 0);
    }
    __syncthreads();

    int s = wave * 16 + ccol;
    bool sv = (s < SS);
    #pragma unroll
    for (int j = 0; j < 4; ++j) {
        int m0 = crow + j;
        e[m0 * 256 + s] = sv ? __expf(acc0[j] * 0.0625f) : 0.f;
    }
    if (crow == 0) {
        #pragma unroll
        for (int j = 0; j < 4; ++j)
            e[(16 + j) * 256 + s] = sv ? __expf(acc1[j] * 0.0625f) : 0.f;
    }
    __syncthreads();

    for (int m = wave; m < NC; m += 16) {
        float v = e[m * 256 + lane] + e[m * 256 + lane + 64] +
                  e[m * 256 + lane + 128] + e[m * 256 + lane + 192];
        #pragma unroll
        for (int off = 32; off >= 1; off >>= 1) v += __shfl_xor(v, off);
        if (lane == 0) ssum[m] = __frcp_rn(v);
    }
    __syncthreads();

    if (t < 256) {
        float r = 0.f;
        #pragma unroll
        for (int h = 0; h < HH; ++h) {
            float p4 = 0.f;
            #pragma unroll
            for (int l = 0; l < LL; ++l) {
                int m = h * LL + l;
                float a = e[m * 256 + t] * ssum[m];
                float a2 = a * a;
                p4 += a2 * a2;
            }
            r += sqrtf(sqrtf(p4));
        }
        pooled[t] = 0.25f * r;
    }
    __syncthreads();

    int d = t & 255, sq = t >> 8;
    float o = 0.f;
    for (int i = 0; i < 50; ++i) {
        int s2 = sq * 50 + i;
        int rw = __builtin_amdgcn_readfirstlane(seq[b * SS + s2]);
        o = fmaf(pooled[s2], emb[(size_t)rw * DD + d], o);
    }
    par[sq * 256 + d] = o;
    __syncthreads();
    if (t < 256) out[(size_t)b * DD + t] =
        par[t] + par[256 + t] + par[512 + t] + par[768 + t];
}

extern "C" void kernel_launch(void* const* d_in, const int* in_sizes, int n_in,
                              void* d_out, int out_size, void* d_ws, size_t ws_size,
                              hipStream_t stream) {
    const int* seq = (const int*)d_in[0];
    const int* slen = (const int*)d_in[1];
    const float* emb = (const float*)d_in[2];
    const float* lin = (const float*)d_in[3];
    const float* wq = (const float*)d_in[4];
    const float* wk = (const float*)d_in[5];
    float* out = (float*)d_out;
    float* ws = (float*)d_ws;

    float* Qt    = ws;                         // [m][b][d] fp32 = 1310720 floats
    float* Upart = ws + 1310720;               // [h][p][d'][e] fp32 = 524288
    unsigned short* ql_bf = (unsigned short*)(ws + 1835008);  // [l][b][e] = 327680 us
    // ends at float offset 1998848 = 8.0 MB

    k_wu3<<<dim3(148), dim3(256), 0, stream>>>(wq, wk, lin, seq, slen, emb, Upart, ql_bf);
    k_qt<<<dim3(160), dim3(256), 0, stream>>>(ql_bf, Upart, Qt);
    k_attn_out<<<dim3(BB), dim3(1024), 0, stream>>>(seq, emb, Qt, out);
}

// Round 15
// 81.381 us; speedup vs baseline: 1.0189x; 1.0189x over previous
//
#include <hip/hip_runtime.h>
#include <hip/hip_bf16.h>

// AttentionMixerRec: B=256 S=200 D=256 V=100000 L=5 H=4
// scores[b,h,l,s] = (ql[b,l] @ U[h]) . emb[b,s] / 16
//   U[h] = WQ[h]^T WK[h];  ql[b,l] = qpre[b,l] @ lin[l]^T;
//   qpre[b,l] = sum of emb rows s in [max(len-1-l,0), len-1].
// v15: v14's 70us k_wu3 was the ql-gather running 16 SERIAL dependent
//     seq->emb load chains per wave (occupancy 1.4%, VALU 1.7%). Fix: slot-
//     major gather -- precompute len/lo for 16 rows (unrolled registers),
//     loop j=0..4 slots with 16 rows' loads in flight (float4 acc[16],
//     static idx). 16-way MLP vs serial. Rest = v14/v13 verbatim.

#define DD 256
#define SS 200
#define BB 256
#define LL 5
#define HH 4
#define NC 20   // H*L
#define P_ER 264   // er pitch in halves
#define P_BF 264   // bf16 slab pitch (2-way bank alias = free)

typedef __attribute__((ext_vector_type(8))) short bf16x8;
typedef __attribute__((ext_vector_type(4))) float f32x4;

__device__ __forceinline__ unsigned short f2bf(float f) {
    __hip_bfloat16 h = __float2bfloat16(f);
    union { __hip_bfloat16 b; unsigned short u; } c; c.b = h; return c.u;
}

// ---- U tile: fp32, K in [ks, ks+128), transposed fp32 epilogue O[j][i] ----
__device__ __forceinline__ void u_tile(const float* __restrict__ A,
                                       const float* __restrict__ B,
                                       float* __restrict__ O,
                                       int tile, int ks, float* lds) {
    float (*As)[68] = (float(*)[68])lds;
    float (*Bs)[68] = (float(*)[68])(lds + 32 * 68);
    int i0 = (tile >> 2) * 64, j0 = (tile & 3) * 64;
    int t = threadIdx.x;
    int tx = t & 15, ty = t >> 4;
    float acc[4][4] = {};
    for (int k0 = ks; k0 < ks + 128; k0 += 32) {
        #pragma unroll
        for (int r = 0; r < 8; ++r) {
            int e = r * 256 + t;
            int kk = e >> 6, ii = e & 63;
            As[kk][ii] = A[(size_t)(k0 + kk) * DD + i0 + ii];
            Bs[kk][ii] = B[(size_t)(k0 + kk) * DD + j0 + ii];
        }
        __syncthreads();
        #pragma unroll
        for (int kk = 0; kk < 32; ++kk) {
            float4 av = *(const float4*)&As[kk][tx * 4];
            float4 bv = *(const float4*)&Bs[kk][ty * 4];
            float a[4] = {av.x, av.y, av.z, av.w};
            float b[4] = {bv.x, bv.y, bv.z, bv.w};
            #pragma unroll
            for (int p = 0; p < 4; ++p)
                #pragma unroll
                for (int q = 0; q < 4; ++q)
                    acc[p][q] += a[p] * b[q];
        }
        __syncthreads();
    }
    #pragma unroll
    for (int q = 0; q < 4; ++q) {
        float4 v = {acc[0][q], acc[1][q], acc[2][q], acc[3][q]};
        *(float4*)&O[(size_t)(j0 + ty * 4 + q) * DD + i0 + tx * 4] = v;
    }
}

// ---- K1: blocks 0..127 = U K-split tiles; 128..147 = ql (MLP gather + MFMA) ----
__global__ __launch_bounds__(256) void k_wu3(const float* __restrict__ wq,
                                             const float* __restrict__ wk,
                                             const float* __restrict__ lin,
                                             const int* __restrict__ seq,
                                             const int* __restrict__ slen,
                                             const float* __restrict__ emb,
                                             float* __restrict__ Upart,
                                             unsigned short* __restrict__ ql_bf) {
    __shared__ char ldsraw[2 * 64 * P_BF * 2];   // 67.6 KB, shared by both paths
    int blk = blockIdx.x, t = threadIdx.x;

    if (blk < 128) {
        int h = blk >> 5, rem = blk & 31;
        int p = rem >> 4, tile = rem & 15;
        u_tile(wq + (size_t)h * 65536, wk + (size_t)h * 65536,
               Upart + (size_t)(h * 2 + p) * 65536, tile, p * 128, (float*)ldsraw);
        return;
    }

    // ---- ql slab: 64 b x 256 e for level l; slot-major MLP gather ----
    int z = blk - 128;
    int l = z >> 2, slab = z & 3;
    int b0 = slab * 64;
    unsigned short* QP = (unsigned short*)ldsraw;   // [64][P_BF] qpre bf16
    unsigned short* SB = QP + 64 * P_BF;            // [64][P_BF] lin chunk bf16
    int lane = t & 63, w = t >> 6;
    int fr = lane & 15, ko = (lane >> 4) * 8;
    int crow = (lane >> 4) * 4, ccol = lane & 15;

    // gather: wave w owns rows {w+4i}, slot-major so 16 loads are in flight
    {
        f32x4 acc[16];
        int len_r[16], lo_r[16];
        #pragma unroll
        for (int i = 0; i < 16; ++i) {
            int b = b0 + w + 4 * i;
            len_r[i] = __builtin_amdgcn_readfirstlane(slen[b]);
            lo_r[i] = max(len_r[i] - 1 - l, 0);
            acc[i] = (f32x4){0.f, 0.f, 0.f, 0.f};
        }
        #pragma unroll
        for (int j = 0; j < 5; ++j) {
            #pragma unroll
            for (int i = 0; i < 16; ++i) {
                int s = lo_r[i] + j;
                if (s < len_r[i]) {     // wave-uniform predicate
                    int b = b0 + w + 4 * i;
                    int row = __builtin_amdgcn_readfirstlane(seq[b * SS + s]);
                    const float4 v = *(const float4*)&emb[(size_t)row * DD + lane * 4];
                    acc[i][0] += v.x; acc[i][1] += v.y;
                    acc[i][2] += v.z; acc[i][3] += v.w;
                }
            }
        }
        #pragma unroll
        for (int i = 0; i < 16; ++i) {
            int r = w + 4 * i;
            ushort4 o;
            o.x = f2bf(acc[i][0]); o.y = f2bf(acc[i][1]);
            o.z = f2bf(acc[i][2]); o.w = f2bf(acc[i][3]);
            *(ushort4*)&QP[r * P_BF + lane * 4] = o;
        }
    }

    for (int ec = 0; ec < 4; ++ec) {
        // stage lin[l][ec*64 + rr][:] fp32 -> bf16 (coalesced full rows)
        for (int rr = w; rr < 64; rr += 4) {
            float4 v = *(const float4*)&lin[(size_t)l * 65536 +
                                            (size_t)(ec * 64 + rr) * DD + lane * 4];
            ushort4 o;
            o.x = f2bf(v.x); o.y = f2bf(v.y); o.z = f2bf(v.z); o.w = f2bf(v.w);
            *(ushort4*)&SB[rr * P_BF + lane * 4] = o;
        }
        __syncthreads();   // first iter also covers QP
        f32x4 accq[4] = {{0.f,0.f,0.f,0.f},{0.f,0.f,0.f,0.f},
                         {0.f,0.f,0.f,0.f},{0.f,0.f,0.f,0.f}};
        for (int kk = 0; kk < 8; ++kk) {
            int kb = kk * 32 + ko;
            bf16x8 a = *(const bf16x8*)&QP[(w * 16 + fr) * P_BF + kb];
            #pragma unroll
            for (int n = 0; n < 4; ++n) {
                bf16x8 bq = *(const bf16x8*)&SB[(n * 16 + fr) * P_BF + kb];
                accq[n] = __builtin_amdgcn_mfma_f32_16x16x32_bf16(a, bq, accq[n], 0, 0, 0);
            }
        }
        // D: row=(lane>>4)*4+j, col=lane&15 [proven]
        #pragma unroll
        for (int n = 0; n < 4; ++n)
            #pragma unroll
            for (int j = 0; j < 4; ++j)
                ql_bf[((size_t)l * 256 + b0 + w * 16 + crow + j) * DD
                      + ec * 64 + n * 16 + ccol] = f2bf(accq[n][j]);
        __syncthreads();   // SB safe to restage
    }
}

// ---- k_qt: Qt[z=h*5+l][b][d'] via bf16 MFMA, tile 128x64, 160 blocks ----
// B-staging sums the two U fp32 partials and converts to bf16 (v11-proven).
__global__ __launch_bounds__(256) void k_qt(const unsigned short* __restrict__ ql_bf,
                                            const float* __restrict__ Upart,
                                            float* __restrict__ Qt) {
    __shared__ unsigned short Asl[128 * P_BF];
    __shared__ unsigned short Bsl[64 * P_BF];
    int blk = blockIdx.x;
    int z = blk >> 3, sub = blk & 7;
    int h = z / 5, l = z % 5;
    int b0 = (sub >> 2) * 128, d0 = (sub & 3) * 64;
    int t = threadIdx.x, lane = t & 63, w = t >> 6;

    const unsigned short* gA = ql_bf + ((size_t)l * 256 + b0) * DD;
    #pragma unroll
    for (int r = 0; r < 16; ++r) {
        int c = r * 256 + t;
        int row = c >> 5, kc = c & 31;
        *(uint4*)&Asl[row * P_BF + kc * 8] = *(const uint4*)&gA[(size_t)row * DD + kc * 8];
    }
    const float* gB0 = Upart + (size_t)(h * 2 + 0) * 65536 + (size_t)d0 * DD;
    const float* gB1 = Upart + (size_t)(h * 2 + 1) * 65536 + (size_t)d0 * DD;
    #pragma unroll
    for (int r = 0; r < 8; ++r) {
        int c = r * 256 + t;
        int row = c >> 5, kc = c & 31;
        float4 u0 = *(const float4*)&gB0[(size_t)row * DD + kc * 8];
        float4 u1 = *(const float4*)&gB0[(size_t)row * DD + kc * 8 + 4];
        float4 v0 = *(const float4*)&gB1[(size_t)row * DD + kc * 8];
        float4 v1 = *(const float4*)&gB1[(size_t)row * DD + kc * 8 + 4];
        ushort4 o0, o1;
        o0.x = f2bf(u0.x + v0.x); o0.y = f2bf(u0.y + v0.y);
        o0.z = f2bf(u0.z + v0.z); o0.w = f2bf(u0.w + v0.w);
        o1.x = f2bf(u1.x + v1.x); o1.y = f2bf(u1.y + v1.y);
        o1.z = f2bf(u1.z + v1.z); o1.w = f2bf(u1.w + v1.w);
        *(ushort4*)&Bsl[row * P_BF + kc * 8] = o0;
        *(ushort4*)&Bsl[row * P_BF + kc * 8 + 4] = o1;
    }
    __syncthreads();

    f32x4 zero = {0.f, 0.f, 0.f, 0.f};
    f32x4 acc[2][4];
    #pragma unroll
    for (int p = 0; p < 2; ++p)
        #pragma unroll
        for (int q = 0; q < 4; ++q) acc[p][q] = zero;

    int ar = w * 32 + (lane & 15);
    int br = lane & 15;
    int ko = (lane >> 4) * 8;
    for (int kk = 0; kk < 8; ++kk) {
        int kb = kk * 32 + ko;
        bf16x8 a0 = *(const bf16x8*)&Asl[(size_t)ar * P_BF + kb];
        bf16x8 a1 = *(const bf16x8*)&Asl[(size_t)(ar + 16) * P_BF + kb];
        bf16x8 b0 = *(const bf16x8*)&Bsl[(size_t)br * P_BF + kb];
        bf16x8 b1 = *(const bf16x8*)&Bsl[(size_t)(br + 16) * P_BF + kb];
        bf16x8 b2 = *(const bf16x8*)&Bsl[(size_t)(br + 32) * P_BF + kb];
        bf16x8 b3 = *(const bf16x8*)&Bsl[(size_t)(br + 48) * P_BF + kb];
        acc[0][0] = __builtin_amdgcn_mfma_f32_16x16x32_bf16(a0, b0, acc[0][0], 0, 0, 0);
        acc[0][1] = __builtin_amdgcn_mfma_f32_16x16x32_bf16(a0, b1, acc[0][1], 0, 0, 0);
        acc[0][2] = __builtin_amdgcn_mfma_f32_16x16x32_bf16(a0, b2, acc[0][2], 0, 0, 0);
        acc[0][3] = __builtin_amdgcn_mfma_f32_16x16x32_bf16(a0, b3, acc[0][3], 0, 0, 0);
        acc[1][0] = __builtin_amdgcn_mfma_f32_16x16x32_bf16(a1, b0, acc[1][0], 0, 0, 0);
        acc[1][1] = __builtin_amdgcn_mfma_f32_16x16x32_bf16(a1, b1, acc[1][1], 0, 0, 0);
        acc[1][2] = __builtin_amdgcn_mfma_f32_16x16x32_bf16(a1, b2, acc[1][2], 0, 0, 0);
        acc[1][3] = __builtin_amdgcn_mfma_f32_16x16x32_bf16(a1, b3, acc[1][3], 0, 0, 0);
    }

    int crow = (lane >> 4) * 4, ccol = lane & 15;
    float* Qb = Qt + (size_t)z * 65536;
    #pragma unroll
    for (int p = 0; p < 2; ++p)
        #pragma unroll
        for (int q = 0; q < 4; ++q)
            #pragma unroll
            for (int j = 0; j < 4; ++j) {
                int row = b0 + w * 32 + p * 16 + crow + j;
                int col = d0 + q * 16 + ccol;
                Qb[(size_t)row * DD + col] = acc[p][q][j];
            }
}

// ---- fused attention (v13 verbatim); phase A = bf16 MFMA ----
__global__ __launch_bounds__(1024, 4) void k_attn_out(const int* __restrict__ seq,
                                                      const float* __restrict__ emb,
                                                      const float* __restrict__ Qt,
                                                      float* __restrict__ out) {
    __shared__ float smem[38016];
    __shared__ float ssum[NC];
    unsigned short* qtb = (unsigned short*)smem;            // [32][P_BF]
    unsigned short* er  = (unsigned short*)(smem + 4224);   // [256][P_ER]
    float* e      = smem + 4224;
    float* pooled = e + NC * 256;
    float* par    = pooled + 256;

    int b = blockIdx.x, t = threadIdx.x;
    int lane = t & 63, wave = t >> 6;

    for (int r = wave; r < 32; r += 16) {
        if (r < NC) {
            float4 v = *(const float4*)&Qt[((size_t)r * BB + b) * DD + lane * 4];
            ushort4 o;
            o.x = f2bf(v.x); o.y = f2bf(v.y); o.z = f2bf(v.z); o.w = f2bf(v.w);
            *(ushort4*)&qtb[r * P_BF + lane * 4] = o;
        } else {
            ushort4 zz = {0, 0, 0, 0};
            *(ushort4*)&qtb[r * P_BF + lane * 4] = zz;
        }
    }
    for (int r = wave; r < 256; r += 16) {
        if (r < SS) {
            int row = __builtin_amdgcn_readfirstlane(seq[b * SS + r]);
            float4 v = *(const float4*)&emb[(size_t)row * DD + lane * 4];
            ushort4 o;
            o.x = f2bf(v.x); o.y = f2bf(v.y); o.z = f2bf(v.z); o.w = f2bf(v.w);
            *(ushort4*)&er[r * P_ER + lane * 4] = o;
        } else {
            ushort4 zz = {0, 0, 0, 0};
            *(ushort4*)&er[r * P_ER + lane * 4] = zz;
        }
    }
    __syncthreads();

    int fr = lane & 15, ko = (lane >> 4) * 8;
    int crow = (lane >> 4) * 4, ccol = lane & 15;
    f32x4 zero4 = {0.f, 0.f, 0.f, 0.f};
    f32x4 acc0 = zero4, acc1 = zero4;
    const unsigned short* erb = er + (wave * 16 + fr) * P_ER;
    #pragma unroll
    for (int kk = 0; kk < 8; ++kk) {
        int kb = kk * 32 + ko;
        bf16x8 bv = *(const bf16x8*)&erb[kb];
        bf16x8 a0 = *(const bf16x8*)&qtb[fr * P_BF + kb];
        bf16x8 a1 = *(const bf16x8*)&qtb[(16 + fr) * P_BF + kb];
        acc0 = __builtin_amdgcn_mfma_f32_16x16x32_bf16(a0, bv, acc0, 0, 0, 0);
        acc1 = __builtin_amdgcn_mfma_f32_16x16x32_bf16(a1, bv, acc1, 0, 0, 0);
    }
    __syncthreads();

    int s = wave * 16 + ccol;
    bool sv = (s < SS);
    #pragma unroll
    for (int j = 0; j < 4; ++j) {
        int m0 = crow + j;
        e[m0 * 256 + s] = sv ? __expf(acc0[j] * 0.0625f) : 0.f;
    }
    if (crow == 0) {
        #pragma unroll
        for (int j = 0; j < 4; ++j)
            e[(16 + j) * 256 + s] = sv ? __expf(acc1[j] * 0.0625f) : 0.f;
    }
    __syncthreads();

    for (int m = wave; m < NC; m += 16) {
        float v = e[m * 256 + lane] + e[m * 256 + lane + 64] +
                  e[m * 256 + lane + 128] + e[m * 256 + lane + 192];
        #pragma unroll
        for (int off = 32; off >= 1; off >>= 1) v += __shfl_xor(v, off);
        if (lane == 0) ssum[m] = __frcp_rn(v);
    }
    __syncthreads();

    if (t < 256) {
        float r = 0.f;
        #pragma unroll
        for (int h = 0; h < HH; ++h) {
            float p4 = 0.f;
            #pragma unroll
            for (int l = 0; l < LL; ++l) {
                int m = h * LL + l;
                float a = e[m * 256 + t] * ssum[m];
                float a2 = a * a;
                p4 += a2 * a2;
            }
            r += sqrtf(sqrtf(p4));
        }
        pooled[t] = 0.25f * r;
    }
    __syncthreads();

    int d = t & 255, sq = t >> 8;
    float o = 0.f;
    for (int i = 0; i < 50; ++i) {
        int s2 = sq * 50 + i;
        int rw = __builtin_amdgcn_readfirstlane(seq[b * SS + s2]);
        o = fmaf(pooled[s2], emb[(size_t)rw * DD + d], o);
    }
    par[sq * 256 + d] = o;
    __syncthreads();
    if (t < 256) out[(size_t)b * DD + t] =
        par[t] + par[256 + t] + par[512 + t] + par[768 + t];
}

extern "C" void kernel_launch(void* const* d_in, const int* in_sizes, int n_in,
                              void* d_out, int out_size, void* d_ws, size_t ws_size,
                              hipStream_t stream) {
    const int* seq = (const int*)d_in[0];
    const int* slen = (const int*)d_in[1];
    const float* emb = (const float*)d_in[2];
    const float* lin = (const float*)d_in[3];
    const float* wq = (const float*)d_in[4];
    const float* wk = (const float*)d_in[5];
    float* out = (float*)d_out;
    float* ws = (float*)d_ws;

    float* Qt    = ws;                         // [m][b][d] fp32 = 1310720 floats
    float* Upart = ws + 1310720;               // [h][p][d'][e] fp32 = 524288
    unsigned short* ql_bf = (unsigned short*)(ws + 1835008);  // [l][b][e] = 327680 us
    // ends at float offset 1998848 = 8.0 MB

    k_wu3<<<dim3(148), dim3(256), 0, stream>>>(wq, wk, lin, seq, slen, emb, Upart, ql_bf);
    k_qt<<<dim3(160), dim3(256), 0, stream>>>(ql_bf, Upart, Qt);
    k_attn_out<<<dim3(BB), dim3(1024), 0, stream>>>(seq, emb, Qt, out);
}

// Round 16
// 48.512 us; speedup vs baseline: 1.7093x; 1.6775x over previous
//
#include <hip/hip_runtime.h>
#include <hip/hip_bf16.h>

// AttentionMixerRec: B=256 S=200 D=256 V=100000 L=5 H=4
// scores[b,h,l,s] = (ql[b,l] @ U[h]) . emb[b,s] / 16
//   U[h] = WQ[h]^T WK[h];  ql[b,l] = qpre[b,l] @ lin[l]^T;
//   qpre[b,l] = sum of emb rows s in [max(len-1-l,0), len-1].
// v16: v14/v15 proved the in-GEMM gather is latency-doomed at 20 blocks
//     (no TLP; serialized s_load chains ~60us regardless of ILP form) ->
//     permanent revert to v13 (52.3us). New: kill remaining serial latency
//     chains: (a) attn stages all 200 seq indices in LDS once, phase C does
//     4 independent emb loads/step; (b) er staging unrolled w/ LDS indices;
//     (c) k_qpre issues all 5 suffix rows in flight (dedup via predicate,
//     same add order); (d) e-pitch 260 kills 4-way store bank conflict.

#define DD 256
#define SS 200
#define BB 256
#define LL 5
#define HH 4
#define NC 20   // H*L
#define P_ER 264   // er pitch in halves
#define P_BF 264   // bf16 slab pitch (2-way bank alias = free)
#define P_E  260   // e overlay pitch in floats

typedef __attribute__((ext_vector_type(8))) short bf16x8;
typedef __attribute__((ext_vector_type(4))) float f32x4;

__device__ __forceinline__ unsigned short f2bf(float f) {
    __hip_bfloat16 h = __float2bfloat16(f);
    union { __hip_bfloat16 b; unsigned short u; } c; c.b = h; return c.u;
}

// ---- U tile: fp32, K in [ks, ks+128), transposed fp32 epilogue O[j][i] ----
__device__ __forceinline__ void u_tile(const float* __restrict__ A,
                                       const float* __restrict__ B,
                                       float* __restrict__ O,
                                       int tile, int ks) {
    __shared__ float As[32][68];
    __shared__ float Bs[32][68];
    int i0 = (tile >> 2) * 64, j0 = (tile & 3) * 64;
    int t = threadIdx.x;
    int tx = t & 15, ty = t >> 4;
    float acc[4][4] = {};
    for (int k0 = ks; k0 < ks + 128; k0 += 32) {
        #pragma unroll
        for (int r = 0; r < 8; ++r) {
            int e = r * 256 + t;
            int kk = e >> 6, ii = e & 63;
            As[kk][ii] = A[(size_t)(k0 + kk) * DD + i0 + ii];
            Bs[kk][ii] = B[(size_t)(k0 + kk) * DD + j0 + ii];
        }
        __syncthreads();
        #pragma unroll
        for (int kk = 0; kk < 32; ++kk) {
            float4 av = *(const float4*)&As[kk][tx * 4];
            float4 bv = *(const float4*)&Bs[kk][ty * 4];
            float a[4] = {av.x, av.y, av.z, av.w};
            float b[4] = {bv.x, bv.y, bv.z, bv.w};
            #pragma unroll
            for (int p = 0; p < 4; ++p)
                #pragma unroll
                for (int q = 0; q < 4; ++q)
                    acc[p][q] += a[p] * b[q];
        }
        __syncthreads();
    }
    #pragma unroll
    for (int q = 0; q < 4; ++q) {
        float4 v = {acc[0][q], acc[1][q], acc[2][q], acc[3][q]};
        *(float4*)&O[(size_t)(j0 + ty * 4 + q) * DD + i0 + tx * 4] = v;
    }
}

// ---- ql tile: fp32 GEMM (A i-major, B j-major), bf16 epilogue O[i][j] ----
__device__ __forceinline__ void ql_tile(const float* __restrict__ A,
                                        const float* __restrict__ B,
                                        unsigned short* __restrict__ O,
                                        int obase_row, int tile) {
    __shared__ float As[32][68];
    __shared__ float Bs[32][68];
    int i0 = (tile >> 2) * 64, j0 = (tile & 3) * 64;
    int t = threadIdx.x;
    int tx = t & 15, ty = t >> 4;
    float acc[4][4] = {};
    for (int k0 = 0; k0 < DD; k0 += 32) {
        #pragma unroll
        for (int r = 0; r < 8; ++r) {
            int e = r * 256 + t;
            int i = e >> 5, k = e & 31;
            As[k][i] = A[(size_t)(i0 + i) * DD + k0 + k];
            Bs[k][i] = B[(size_t)(j0 + i) * DD + k0 + k];
        }
        __syncthreads();
        #pragma unroll
        for (int kk = 0; kk < 32; ++kk) {
            float4 av = *(const float4*)&As[kk][tx * 4];
            float4 bv = *(const float4*)&Bs[kk][ty * 4];
            float a[4] = {av.x, av.y, av.z, av.w};
            float b[4] = {bv.x, bv.y, bv.z, bv.w};
            #pragma unroll
            for (int p = 0; p < 4; ++p)
                #pragma unroll
                for (int q = 0; q < 4; ++q)
                    acc[p][q] += a[p] * b[q];
        }
        __syncthreads();
    }
    #pragma unroll
    for (int p = 0; p < 4; ++p) {
        ushort4 v;
        v.x = f2bf(acc[p][0]); v.y = f2bf(acc[p][1]);
        v.z = f2bf(acc[p][2]); v.w = f2bf(acc[p][3]);
        *(ushort4*)&O[(size_t)(obase_row + i0 + tx * 4 + p) * DD + j0 + ty * 4] = v;
    }
}

// ---- k_qpre: suffix gather, 5 rows in flight (256 blocks) ----
__global__ __launch_bounds__(256) void k_qpre(const int* __restrict__ seq,
                                              const int* __restrict__ slen,
                                              const float* __restrict__ emb,
                                              float* __restrict__ qpre) {
    __shared__ int rows[256];
    int b = blockIdx.x, t = threadIdx.x;
    rows[t] = (t < SS) ? seq[b * SS + t] : 0;   // one coalesced load
    __syncthreads();
    int len = slen[b];
    int p[LL];
    #pragma unroll
    for (int l = 0; l < LL; ++l) p[l] = max(len - 1 - l, 0);
    float v[LL];
    #pragma unroll
    for (int l = 0; l < LL; ++l)                 // 5 independent loads in flight
        v[l] = emb[(size_t)rows[p[l]] * DD + t];
    float acc = v[0];
    qpre[(size_t)b * DD + t] = acc;              // l=0 plane
    #pragma unroll
    for (int l = 1; l < LL; ++l) {
        if (p[l] != p[l - 1]) acc += v[l];       // dedup at clamped 0
        qpre[(size_t)(l * BB + b) * DD + t] = acc;
    }
}

// ---- k_wu2: blocks 0..127 = U K-split tiles (fp32); 128..207 = ql tiles ----
__global__ __launch_bounds__(256) void k_wu2(const float* __restrict__ wq,
                                             const float* __restrict__ wk,
                                             const float* __restrict__ qpre,
                                             const float* __restrict__ lin,
                                             float* __restrict__ Upart,
                                             unsigned short* __restrict__ ql_bf) {
    int blk = blockIdx.x;
    if (blk < 128) {
        int h = blk >> 5, rem = blk & 31;
        int p = rem >> 4, tile = rem & 15;
        u_tile(wq + (size_t)h * 65536, wk + (size_t)h * 65536,
               Upart + (size_t)(h * 2 + p) * 65536, tile, p * 128);
    } else {
        int z = blk - 128;
        int l = z >> 4;
        ql_tile(qpre + (size_t)l * 65536, lin + (size_t)l * 65536,
                ql_bf, l * 256, z & 15);
    }
}

// ---- k_qt: Qt[z=h*5+l][b][d'] via bf16 MFMA, tile 128x64, 160 blocks ----
__global__ __launch_bounds__(256) void k_qt(const unsigned short* __restrict__ ql_bf,
                                            const float* __restrict__ Upart,
                                            float* __restrict__ Qt) {
    __shared__ unsigned short Asl[128 * P_BF];
    __shared__ unsigned short Bsl[64 * P_BF];
    int blk = blockIdx.x;
    int z = blk >> 3, sub = blk & 7;
    int h = z / 5, l = z % 5;
    int b0 = (sub >> 2) * 128, d0 = (sub & 3) * 64;
    int t = threadIdx.x, lane = t & 63, w = t >> 6;

    const unsigned short* gA = ql_bf + ((size_t)l * 256 + b0) * DD;
    #pragma unroll
    for (int r = 0; r < 16; ++r) {
        int c = r * 256 + t;
        int row = c >> 5, kc = c & 31;
        *(uint4*)&Asl[row * P_BF + kc * 8] = *(const uint4*)&gA[(size_t)row * DD + kc * 8];
    }
    const float* gB0 = Upart + (size_t)(h * 2 + 0) * 65536 + (size_t)d0 * DD;
    const float* gB1 = Upart + (size_t)(h * 2 + 1) * 65536 + (size_t)d0 * DD;
    #pragma unroll
    for (int r = 0; r < 8; ++r) {
        int c = r * 256 + t;
        int row = c >> 5, kc = c & 31;
        float4 u0 = *(const float4*)&gB0[(size_t)row * DD + kc * 8];
        float4 u1 = *(const float4*)&gB0[(size_t)row * DD + kc * 8 + 4];
        float4 v0 = *(const float4*)&gB1[(size_t)row * DD + kc * 8];
        float4 v1 = *(const float4*)&gB1[(size_t)row * DD + kc * 8 + 4];
        ushort4 o0, o1;
        o0.x = f2bf(u0.x + v0.x); o0.y = f2bf(u0.y + v0.y);
        o0.z = f2bf(u0.z + v0.z); o0.w = f2bf(u0.w + v0.w);
        o1.x = f2bf(u1.x + v1.x); o1.y = f2bf(u1.y + v1.y);
        o1.z = f2bf(u1.z + v1.z); o1.w = f2bf(u1.w + v1.w);
        *(ushort4*)&Bsl[row * P_BF + kc * 8] = o0;
        *(ushort4*)&Bsl[row * P_BF + kc * 8 + 4] = o1;
    }
    __syncthreads();

    f32x4 zero = {0.f, 0.f, 0.f, 0.f};
    f32x4 acc[2][4];
    #pragma unroll
    for (int p = 0; p < 2; ++p)
        #pragma unroll
        for (int q = 0; q < 4; ++q) acc[p][q] = zero;

    int ar = w * 32 + (lane & 15);
    int br = lane & 15;
    int ko = (lane >> 4) * 8;
    for (int kk = 0; kk < 8; ++kk) {
        int kb = kk * 32 + ko;
        bf16x8 a0 = *(const bf16x8*)&Asl[(size_t)ar * P_BF + kb];
        bf16x8 a1 = *(const bf16x8*)&Asl[(size_t)(ar + 16) * P_BF + kb];
        bf16x8 b0 = *(const bf16x8*)&Bsl[(size_t)br * P_BF + kb];
        bf16x8 b1 = *(const bf16x8*)&Bsl[(size_t)(br + 16) * P_BF + kb];
        bf16x8 b2 = *(const bf16x8*)&Bsl[(size_t)(br + 32) * P_BF + kb];
        bf16x8 b3 = *(const bf16x8*)&Bsl[(size_t)(br + 48) * P_BF + kb];
        acc[0][0] = __builtin_amdgcn_mfma_f32_16x16x32_bf16(a0, b0, acc[0][0], 0, 0, 0);
        acc[0][1] = __builtin_amdgcn_mfma_f32_16x16x32_bf16(a0, b1, acc[0][1], 0, 0, 0);
        acc[0][2] = __builtin_amdgcn_mfma_f32_16x16x32_bf16(a0, b2, acc[0][2], 0, 0, 0);
        acc[0][3] = __builtin_amdgcn_mfma_f32_16x16x32_bf16(a0, b3, acc[0][3], 0, 0, 0);
        acc[1][0] = __builtin_amdgcn_mfma_f32_16x16x32_bf16(a1, b0, acc[1][0], 0, 0, 0);
        acc[1][1] = __builtin_amdgcn_mfma_f32_16x16x32_bf16(a1, b1, acc[1][1], 0, 0, 0);
        acc[1][2] = __builtin_amdgcn_mfma_f32_16x16x32_bf16(a1, b2, acc[1][2], 0, 0, 0);
        acc[1][3] = __builtin_amdgcn_mfma_f32_16x16x32_bf16(a1, b3, acc[1][3], 0, 0, 0);
    }

    int crow = (lane >> 4) * 4, ccol = lane & 15;
    float* Qb = Qt + (size_t)z * 65536;
    #pragma unroll
    for (int p = 0; p < 2; ++p)
        #pragma unroll
        for (int q = 0; q < 4; ++q)
            #pragma unroll
            for (int j = 0; j < 4; ++j) {
                int row = b0 + w * 32 + p * 16 + crow + j;
                int col = d0 + q * 16 + ccol;
                Qb[(size_t)row * DD + col] = acc[p][q][j];
            }
}

// ---- fused attention; phase A = bf16 MFMA; seq indices staged in LDS ----
__global__ __launch_bounds__(1024, 4) void k_attn_out(const int* __restrict__ seq,
                                                      const float* __restrict__ emb,
                                                      const float* __restrict__ Qt,
                                                      float* __restrict__ out) {
    __shared__ float smem[38016];
    __shared__ float ssum[NC];
    __shared__ int rowsl[256];
    unsigned short* qtb = (unsigned short*)smem;            // [32][P_BF]
    unsigned short* er  = (unsigned short*)(smem + 4224);   // [256][P_ER]
    float* e      = smem + 4224;          // overlay after phase A, pitch P_E
    float* pooled = e + NC * P_E;
    float* par    = pooled + 256;

    int b = blockIdx.x, t = threadIdx.x;
    int lane = t & 63, wave = t >> 6;

    if (t < 256) rowsl[t] = (t < SS) ? seq[b * SS + t] : 0;  // one coalesced load
    __syncthreads();

    for (int r = wave; r < 32; r += 16) {
        if (r < NC) {
            float4 v = *(const float4*)&Qt[((size_t)r * BB + b) * DD + lane * 4];
            ushort4 o;
            o.x = f2bf(v.x); o.y = f2bf(v.y); o.z = f2bf(v.z); o.w = f2bf(v.w);
            *(ushort4*)&qtb[r * P_BF + lane * 4] = o;
        } else {
            ushort4 zz = {0, 0, 0, 0};
            *(ushort4*)&qtb[r * P_BF + lane * 4] = zz;
        }
    }
    #pragma unroll
    for (int k = 0; k < 16; ++k) {
        int r = wave + k * 16;
        if (r < SS) {
            int row = __builtin_amdgcn_readfirstlane(rowsl[r]);
            float4 v = *(const float4*)&emb[(size_t)row * DD + lane * 4];
            ushort4 o;
            o.x = f2bf(v.x); o.y = f2bf(v.y); o.z = f2bf(v.z); o.w = f2bf(v.w);
            *(ushort4*)&er[r * P_ER + lane * 4] = o;
        } else {
            ushort4 zz = {0, 0, 0, 0};
            *(ushort4*)&er[r * P_ER + lane * 4] = zz;
        }
    }
    __syncthreads();

    int fr = lane & 15, ko = (lane >> 4) * 8;
    int crow = (lane >> 4) * 4, ccol = lane & 15;
    f32x4 zero4 = {0.f, 0.f, 0.f, 0.f};
    f32x4 acc0 = zero4, acc1 = zero4;
    const unsigned short* erb = er + (wave * 16 + fr) * P_ER;
    #pragma unroll
    for (int kk = 0; kk < 8; ++kk) {
        int kb = kk * 32 + ko;
        bf16x8 bv = *(const bf16x8*)&erb[kb];
        bf16x8 a0 = *(const bf16x8*)&qtb[fr * P_BF + kb];
        bf16x8 a1 = *(const bf16x8*)&qtb[(16 + fr) * P_BF + kb];
        acc0 = __builtin_amdgcn_mfma_f32_16x16x32_bf16(a0, bv, acc0, 0, 0, 0);
        acc1 = __builtin_amdgcn_mfma_f32_16x16x32_bf16(a1, bv, acc1, 0, 0, 0);
    }
    __syncthreads();

    int s = wave * 16 + ccol;
    bool sv = (s < SS);
    #pragma unroll
    for (int j = 0; j < 4; ++j) {
        int m0 = crow + j;
        e[m0 * P_E + s] = sv ? __expf(acc0[j] * 0.0625f) : 0.f;
    }
    if (crow == 0) {
        #pragma unroll
        for (int j = 0; j < 4; ++j)
            e[(16 + j) * P_E + s] = sv ? __expf(acc1[j] * 0.0625f) : 0.f;
    }
    __syncthreads();

    for (int m = wave; m < NC; m += 16) {
        float v = e[m * P_E + lane] + e[m * P_E + lane + 64] +
                  e[m * P_E + lane + 128] + e[m * P_E + lane + 192];
        #pragma unroll
        for (int off = 32; off >= 1; off >>= 1) v += __shfl_xor(v, off);
        if (lane == 0) ssum[m] = __frcp_rn(v);
    }
    __syncthreads();

    if (t < 256) {
        float r = 0.f;
        #pragma unroll
        for (int h = 0; h < HH; ++h) {
            float p4 = 0.f;
            #pragma unroll
            for (int l = 0; l < LL; ++l) {
                int m = h * LL + l;
                float a = e[m * P_E + t] * ssum[m];
                float a2 = a * a;
                p4 += a2 * a2;
            }
            r += sqrtf(sqrtf(p4));
        }
        pooled[t] = 0.25f * r;
    }
    __syncthreads();

    // phase C: 4 independent emb loads per step (indices from LDS)
    int d = t & 255, sq = t >> 8;
    int sbase = sq * 50;
    float o = 0.f;
    for (int i = 0; i < 48; i += 4) {
        int r0 = __builtin_amdgcn_readfirstlane(rowsl[sbase + i]);
        int r1 = __builtin_amdgcn_readfirstlane(rowsl[sbase + i + 1]);
        int r2 = __builtin_amdgcn_readfirstlane(rowsl[sbase + i + 2]);
        int r3 = __builtin_amdgcn_readfirstlane(rowsl[sbase + i + 3]);
        float e0 = emb[(size_t)r0 * DD + d];
        float e1 = emb[(size_t)r1 * DD + d];
        float e2 = emb[(size_t)r2 * DD + d];
        float e3 = emb[(size_t)r3 * DD + d];
        o = fmaf(pooled[sbase + i], e0, o);
        o = fmaf(pooled[sbase + i + 1], e1, o);
        o = fmaf(pooled[sbase + i + 2], e2, o);
        o = fmaf(pooled[sbase + i + 3], e3, o);
    }
    {
        int r0 = __builtin_amdgcn_readfirstlane(rowsl[sbase + 48]);
        int r1 = __builtin_amdgcn_readfirstlane(rowsl[sbase + 49]);
        float e0 = emb[(size_t)r0 * DD + d];
        float e1 = emb[(size_t)r1 * DD + d];
        o = fmaf(pooled[sbase + 48], e0, o);
        o = fmaf(pooled[sbase + 49], e1, o);
    }
    par[sq * 256 + d] = o;
    __syncthreads();
    if (t < 256) out[(size_t)b * DD + t] =
        par[t] + par[256 + t] + par[512 + t] + par[768 + t];
}

extern "C" void kernel_launch(void* const* d_in, const int* in_sizes, int n_in,
                              void* d_out, int out_size, void* d_ws, size_t ws_size,
                              hipStream_t stream) {
    const int* seq = (const int*)d_in[0];
    const int* slen = (const int*)d_in[1];
    const float* emb = (const float*)d_in[2];
    const float* lin = (const float*)d_in[3];
    const float* wq = (const float*)d_in[4];
    const float* wk = (const float*)d_in[5];
    float* out = (float*)d_out;
    float* ws = (float*)d_ws;

    float* qpre  = ws;                         // [l][b][d] fp32 = 327680 floats
    float* Qt    = ws + 327680;                // [m][b][d] fp32 = 1310720
    float* Upart = ws + 1638400;               // [h][p][d'][e] fp32 = 524288
    unsigned short* ql_bf = (unsigned short*)(ws + 2162688);  // [l][b][e] = 327680 us
    // ends at float offset 2326528 = 9.3 MB

    k_qpre<<<dim3(BB), dim3(256), 0, stream>>>(seq, slen, emb, qpre);
    k_wu2<<<dim3(208), dim3(256), 0, stream>>>(wq, wk, qpre, lin, Upart, ql_bf);
    k_qt<<<dim3(160), dim3(256), 0, stream>>>(ql_bf, Upart, Qt);
    k_attn_out<<<dim3(BB), dim3(1024), 0, stream>>>(seq, emb, Qt, out);
}

// Round 17
// 44.869 us; speedup vs baseline: 1.8481x; 1.0812x over previous
//
#include <hip/hip_runtime.h>
#include <hip/hip_bf16.h>

// AttentionMixerRec: B=256 S=200 D=256 V=100000 L=5 H=4
// scores[b,h,l,s] = (ql[b,l] @ U[h]) . emb[b,s] / 16
//   U[h] = WQ[h]^T WK[h];  ql[b,l] = qpre[b,l] @ lin[l]^T;
//   qpre[b,l] = sum of emb rows s in [max(len-1-l,0), len-1].
// v17: v16 (48.5us) + (a) attn phase C reads er (bf16, LDS) instead of
//     re-fetching 51MB of emb rows from global; e/pooled/par overlay moved
//     to er rows 200..255 (dead after phase-A MFMA zero-padding) so er rows
//     0..199 stay live; (b) Qt stored bf16 (attn bf16-converts it anyway) --
//     halves Qt traffic, staging becomes a raw copy. 4-launch DAG is forced
//     (3 dependent GEMM levels; device sync proven 100+us). Rest = v16.

#define DD 256
#define SS 200
#define BB 256
#define LL 5
#define HH 4
#define NC 20   // H*L
#define P_ER 264   // er pitch in halves (16B-aligned rows, MFMA-conflict-free)
#define P_BF 264   // bf16 slab pitch (2-way bank alias = free)
#define P_E  260   // e overlay pitch in floats (2-way store alias = free)

typedef __attribute__((ext_vector_type(8))) short bf16x8;
typedef __attribute__((ext_vector_type(4))) float f32x4;

__device__ __forceinline__ unsigned short f2bf(float f) {
    __hip_bfloat16 h = __float2bfloat16(f);
    union { __hip_bfloat16 b; unsigned short u; } c; c.b = h; return c.u;
}
__device__ __forceinline__ float bf2f(unsigned short u) {
    union { unsigned i; float f; } c; c.i = (unsigned)u << 16; return c.f;
}

// ---- U tile: fp32, K in [ks, ks+128), transposed fp32 epilogue O[j][i] ----
__device__ __forceinline__ void u_tile(const float* __restrict__ A,
                                       const float* __restrict__ B,
                                       float* __restrict__ O,
                                       int tile, int ks) {
    __shared__ float As[32][68];
    __shared__ float Bs[32][68];
    int i0 = (tile >> 2) * 64, j0 = (tile & 3) * 64;
    int t = threadIdx.x;
    int tx = t & 15, ty = t >> 4;
    float acc[4][4] = {};
    for (int k0 = ks; k0 < ks + 128; k0 += 32) {
        #pragma unroll
        for (int r = 0; r < 8; ++r) {
            int e = r * 256 + t;
            int kk = e >> 6, ii = e & 63;
            As[kk][ii] = A[(size_t)(k0 + kk) * DD + i0 + ii];
            Bs[kk][ii] = B[(size_t)(k0 + kk) * DD + j0 + ii];
        }
        __syncthreads();
        #pragma unroll
        for (int kk = 0; kk < 32; ++kk) {
            float4 av = *(const float4*)&As[kk][tx * 4];
            float4 bv = *(const float4*)&Bs[kk][ty * 4];
            float a[4] = {av.x, av.y, av.z, av.w};
            float b[4] = {bv.x, bv.y, bv.z, bv.w};
            #pragma unroll
            for (int p = 0; p < 4; ++p)
                #pragma unroll
                for (int q = 0; q < 4; ++q)
                    acc[p][q] += a[p] * b[q];
        }
        __syncthreads();
    }
    #pragma unroll
    for (int q = 0; q < 4; ++q) {
        float4 v = {acc[0][q], acc[1][q], acc[2][q], acc[3][q]};
        *(float4*)&O[(size_t)(j0 + ty * 4 + q) * DD + i0 + tx * 4] = v;
    }
}

// ---- ql tile: fp32 GEMM (A i-major, B j-major), bf16 epilogue O[i][j] ----
__device__ __forceinline__ void ql_tile(const float* __restrict__ A,
                                        const float* __restrict__ B,
                                        unsigned short* __restrict__ O,
                                        int obase_row, int tile) {
    __shared__ float As[32][68];
    __shared__ float Bs[32][68];
    int i0 = (tile >> 2) * 64, j0 = (tile & 3) * 64;
    int t = threadIdx.x;
    int tx = t & 15, ty = t >> 4;
    float acc[4][4] = {};
    for (int k0 = 0; k0 < DD; k0 += 32) {
        #pragma unroll
        for (int r = 0; r < 8; ++r) {
            int e = r * 256 + t;
            int i = e >> 5, k = e & 31;
            As[k][i] = A[(size_t)(i0 + i) * DD + k0 + k];
            Bs[k][i] = B[(size_t)(j0 + i) * DD + k0 + k];
        }
        __syncthreads();
        #pragma unroll
        for (int kk = 0; kk < 32; ++kk) {
            float4 av = *(const float4*)&As[kk][tx * 4];
            float4 bv = *(const float4*)&Bs[kk][ty * 4];
            float a[4] = {av.x, av.y, av.z, av.w};
            float b[4] = {bv.x, bv.y, bv.z, bv.w};
            #pragma unroll
            for (int p = 0; p < 4; ++p)
                #pragma unroll
                for (int q = 0; q < 4; ++q)
                    acc[p][q] += a[p] * b[q];
        }
        __syncthreads();
    }
    #pragma unroll
    for (int p = 0; p < 4; ++p) {
        ushort4 v;
        v.x = f2bf(acc[p][0]); v.y = f2bf(acc[p][1]);
        v.z = f2bf(acc[p][2]); v.w = f2bf(acc[p][3]);
        *(ushort4*)&O[(size_t)(obase_row + i0 + tx * 4 + p) * DD + j0 + ty * 4] = v;
    }
}

// ---- k_qpre: suffix gather, 5 rows in flight (256 blocks) ----
__global__ __launch_bounds__(256) void k_qpre(const int* __restrict__ seq,
                                              const int* __restrict__ slen,
                                              const float* __restrict__ emb,
                                              float* __restrict__ qpre) {
    __shared__ int rows[256];
    int b = blockIdx.x, t = threadIdx.x;
    rows[t] = (t < SS) ? seq[b * SS + t] : 0;
    __syncthreads();
    int len = slen[b];
    int p[LL];
    #pragma unroll
    for (int l = 0; l < LL; ++l) p[l] = max(len - 1 - l, 0);
    float v[LL];
    #pragma unroll
    for (int l = 0; l < LL; ++l)
        v[l] = emb[(size_t)rows[p[l]] * DD + t];
    float acc = v[0];
    qpre[(size_t)b * DD + t] = acc;
    #pragma unroll
    for (int l = 1; l < LL; ++l) {
        if (p[l] != p[l - 1]) acc += v[l];
        qpre[(size_t)(l * BB + b) * DD + t] = acc;
    }
}

// ---- k_wu2: blocks 0..127 = U K-split tiles (fp32); 128..207 = ql tiles ----
__global__ __launch_bounds__(256) void k_wu2(const float* __restrict__ wq,
                                             const float* __restrict__ wk,
                                             const float* __restrict__ qpre,
                                             const float* __restrict__ lin,
                                             float* __restrict__ Upart,
                                             unsigned short* __restrict__ ql_bf) {
    int blk = blockIdx.x;
    if (blk < 128) {
        int h = blk >> 5, rem = blk & 31;
        int p = rem >> 4, tile = rem & 15;
        u_tile(wq + (size_t)h * 65536, wk + (size_t)h * 65536,
               Upart + (size_t)(h * 2 + p) * 65536, tile, p * 128);
    } else {
        int z = blk - 128;
        int l = z >> 4;
        ql_tile(qpre + (size_t)l * 65536, lin + (size_t)l * 65536,
                ql_bf, l * 256, z & 15);
    }
}

// ---- k_qt: Qt_bf[z=h*5+l][b][d'] via bf16 MFMA, tile 128x64, 160 blocks ----
__global__ __launch_bounds__(256) void k_qt(const unsigned short* __restrict__ ql_bf,
                                            const float* __restrict__ Upart,
                                            unsigned short* __restrict__ Qt_bf) {
    __shared__ unsigned short Asl[128 * P_BF];
    __shared__ unsigned short Bsl[64 * P_BF];
    int blk = blockIdx.x;
    int z = blk >> 3, sub = blk & 7;
    int h = z / 5, l = z % 5;
    int b0 = (sub >> 2) * 128, d0 = (sub & 3) * 64;
    int t = threadIdx.x, lane = t & 63, w = t >> 6;

    const unsigned short* gA = ql_bf + ((size_t)l * 256 + b0) * DD;
    #pragma unroll
    for (int r = 0; r < 16; ++r) {
        int c = r * 256 + t;
        int row = c >> 5, kc = c & 31;
        *(uint4*)&Asl[row * P_BF + kc * 8] = *(const uint4*)&gA[(size_t)row * DD + kc * 8];
    }
    const float* gB0 = Upart + (size_t)(h * 2 + 0) * 65536 + (size_t)d0 * DD;
    const float* gB1 = Upart + (size_t)(h * 2 + 1) * 65536 + (size_t)d0 * DD;
    #pragma unroll
    for (int r = 0; r < 8; ++r) {
        int c = r * 256 + t;
        int row = c >> 5, kc = c & 31;
        float4 u0 = *(const float4*)&gB0[(size_t)row * DD + kc * 8];
        float4 u1 = *(const float4*)&gB0[(size_t)row * DD + kc * 8 + 4];
        float4 v0 = *(const float4*)&gB1[(size_t)row * DD + kc * 8];
        float4 v1 = *(const float4*)&gB1[(size_t)row * DD + kc * 8 + 4];
        ushort4 o0, o1;
        o0.x = f2bf(u0.x + v0.x); o0.y = f2bf(u0.y + v0.y);
        o0.z = f2bf(u0.z + v0.z); o0.w = f2bf(u0.w + v0.w);
        o1.x = f2bf(u1.x + v1.x); o1.y = f2bf(u1.y + v1.y);
        o1.z = f2bf(u1.z + v1.z); o1.w = f2bf(u1.w + v1.w);
        *(ushort4*)&Bsl[row * P_BF + kc * 8] = o0;
        *(ushort4*)&Bsl[row * P_BF + kc * 8 + 4] = o1;
    }
    __syncthreads();

    f32x4 zero = {0.f, 0.f, 0.f, 0.f};
    f32x4 acc[2][4];
    #pragma unroll
    for (int p = 0; p < 2; ++p)
        #pragma unroll
        for (int q = 0; q < 4; ++q) acc[p][q] = zero;

    int ar = w * 32 + (lane & 15);
    int br = lane & 15;
    int ko = (lane >> 4) * 8;
    for (int kk = 0; kk < 8; ++kk) {
        int kb = kk * 32 + ko;
        bf16x8 a0 = *(const bf16x8*)&Asl[(size_t)ar * P_BF + kb];
        bf16x8 a1 = *(const bf16x8*)&Asl[(size_t)(ar + 16) * P_BF + kb];
        bf16x8 b0 = *(const bf16x8*)&Bsl[(size_t)br * P_BF + kb];
        bf16x8 b1 = *(const bf16x8*)&Bsl[(size_t)(br + 16) * P_BF + kb];
        bf16x8 b2 = *(const bf16x8*)&Bsl[(size_t)(br + 32) * P_BF + kb];
        bf16x8 b3 = *(const bf16x8*)&Bsl[(size_t)(br + 48) * P_BF + kb];
        acc[0][0] = __builtin_amdgcn_mfma_f32_16x16x32_bf16(a0, b0, acc[0][0], 0, 0, 0);
        acc[0][1] = __builtin_amdgcn_mfma_f32_16x16x32_bf16(a0, b1, acc[0][1], 0, 0, 0);
        acc[0][2] = __builtin_amdgcn_mfma_f32_16x16x32_bf16(a0, b2, acc[0][2], 0, 0, 0);
        acc[0][3] = __builtin_amdgcn_mfma_f32_16x16x32_bf16(a0, b3, acc[0][3], 0, 0, 0);
        acc[1][0] = __builtin_amdgcn_mfma_f32_16x16x32_bf16(a1, b0, acc[1][0], 0, 0, 0);
        acc[1][1] = __builtin_amdgcn_mfma_f32_16x16x32_bf16(a1, b1, acc[1][1], 0, 0, 0);
        acc[1][2] = __builtin_amdgcn_mfma_f32_16x16x32_bf16(a1, b2, acc[1][2], 0, 0, 0);
        acc[1][3] = __builtin_amdgcn_mfma_f32_16x16x32_bf16(a1, b3, acc[1][3], 0, 0, 0);
    }

    int crow = (lane >> 4) * 4, ccol = lane & 15;
    unsigned short* Qb = Qt_bf + (size_t)z * 65536;
    #pragma unroll
    for (int p = 0; p < 2; ++p)
        #pragma unroll
        for (int q = 0; q < 4; ++q)
            #pragma unroll
            for (int j = 0; j < 4; ++j) {
                int row = b0 + w * 32 + p * 16 + crow + j;
                int col = d0 + q * 16 + ccol;
                Qb[(size_t)row * DD + col] = f2bf(acc[p][q][j]);
            }
}

// ---- fused attention; phase A = bf16 MFMA; phase C from LDS er ----
// LDS map (floats): qtb [0,4224) | er [4224,38016) (256 rows x 264 halves)
//   overlay in er rows 200..255 (dead after phase A):
//   e = 30624 (20 x P_E) | pooled = 35824 | par = 36080..37104
__global__ __launch_bounds__(1024, 4) void k_attn_out(const int* __restrict__ seq,
                                                      const float* __restrict__ emb,
                                                      const unsigned short* __restrict__ Qt_bf,
                                                      float* __restrict__ out) {
    __shared__ float smem[38016];
    __shared__ float ssum[NC];
    __shared__ int rowsl[256];
    unsigned short* qtb = (unsigned short*)smem;            // [32][P_BF]
    unsigned short* er  = (unsigned short*)(smem + 4224);   // [256][P_ER]
    float* e      = smem + 30624;          // rows 200.. overlay, pitch P_E
    float* pooled = smem + 35824;
    float* par    = smem + 36080;

    int b = blockIdx.x, t = threadIdx.x;
    int lane = t & 63, wave = t >> 6;

    if (t < 256) rowsl[t] = (t < SS) ? seq[b * SS + t] : 0;
    __syncthreads();

    // stage qtb: raw bf16 copy of Qt_bf rows, zero rows 20..31
    for (int r = wave; r < 32; r += 16) {
        if (r < NC) {
            uint2 v = *(const uint2*)&Qt_bf[((size_t)r * BB + b) * DD + lane * 4];
            *(uint2*)&qtb[r * P_BF + lane * 4] = v;
        } else {
            *(uint2*)&qtb[r * P_BF + lane * 4] = make_uint2(0u, 0u);
        }
    }
    // stage er: 200 emb rows bf16, zero rows 200..255
    #pragma unroll
    for (int k = 0; k < 16; ++k) {
        int r = wave + k * 16;
        if (r < SS) {
            int row = __builtin_amdgcn_readfirstlane(rowsl[r]);
            float4 v = *(const float4*)&emb[(size_t)row * DD + lane * 4];
            ushort4 o;
            o.x = f2bf(v.x); o.y = f2bf(v.y); o.z = f2bf(v.z); o.w = f2bf(v.w);
            *(ushort4*)&er[r * P_ER + lane * 4] = o;
        } else {
            ushort4 zz = {0, 0, 0, 0};
            *(ushort4*)&er[r * P_ER + lane * 4] = zz;
        }
    }
    __syncthreads();

    // phase A MFMA: wave = s-tile (16 s), m-tiles 0..1 (rows 0..31)
    int fr = lane & 15, ko = (lane >> 4) * 8;
    int crow = (lane >> 4) * 4, ccol = lane & 15;
    f32x4 zero4 = {0.f, 0.f, 0.f, 0.f};
    f32x4 acc0 = zero4, acc1 = zero4;
    const unsigned short* erb = er + (wave * 16 + fr) * P_ER;
    #pragma unroll
    for (int kk = 0; kk < 8; ++kk) {
        int kb = kk * 32 + ko;
        bf16x8 bv = *(const bf16x8*)&erb[kb];
        bf16x8 a0 = *(const bf16x8*)&qtb[fr * P_BF + kb];
        bf16x8 a1 = *(const bf16x8*)&qtb[(16 + fr) * P_BF + kb];
        acc0 = __builtin_amdgcn_mfma_f32_16x16x32_bf16(a0, bv, acc0, 0, 0, 0);
        acc1 = __builtin_amdgcn_mfma_f32_16x16x32_bf16(a1, bv, acc1, 0, 0, 0);
    }
    __syncthreads();   // all er row-200+ zero-reads done before overlay writes

    int s = wave * 16 + ccol;
    bool sv = (s < SS);
    #pragma unroll
    for (int j = 0; j < 4; ++j) {
        int m0 = crow + j;
        e[m0 * P_E + s] = sv ? __expf(acc0[j] * 0.0625f) : 0.f;
    }
    if (crow == 0) {
        #pragma unroll
        for (int j = 0; j < 4; ++j)
            e[(16 + j) * P_E + s] = sv ? __expf(acc1[j] * 0.0625f) : 0.f;
    }
    __syncthreads();

    for (int m = wave; m < NC; m += 16) {
        float v = e[m * P_E + lane] + e[m * P_E + lane + 64] +
                  e[m * P_E + lane + 128] + e[m * P_E + lane + 192];
        #pragma unroll
        for (int off = 32; off >= 1; off >>= 1) v += __shfl_xor(v, off);
        if (lane == 0) ssum[m] = __frcp_rn(v);
    }
    __syncthreads();

    if (t < 256) {
        float r = 0.f;
        #pragma unroll
        for (int h = 0; h < HH; ++h) {
            float p4 = 0.f;
            #pragma unroll
            for (int l = 0; l < LL; ++l) {
                int m = h * LL + l;
                float a = e[m * P_E + t] * ssum[m];
                float a2 = a * a;
                p4 += a2 * a2;
            }
            r += sqrtf(sqrtf(p4));
        }
        pooled[t] = 0.25f * r;
    }
    __syncthreads();

    // phase C: out[b,d] = sum_s pooled[s] * er[s][d]  (LDS bf16, no global)
    int d = t & 255, sq = t >> 8;
    int sbase = sq * 50;
    float o = 0.f;
    #pragma unroll 10
    for (int i = 0; i < 50; ++i) {
        int s2 = sbase + i;
        o = fmaf(pooled[s2], bf2f(er[s2 * P_ER + d]), o);
    }
    par[sq * 256 + d] = o;
    __syncthreads();
    if (t < 256) out[(size_t)b * DD + t] =
        par[t] + par[256 + t] + par[512 + t] + par[768 + t];
}

extern "C" void kernel_launch(void* const* d_in, const int* in_sizes, int n_in,
                              void* d_out, int out_size, void* d_ws, size_t ws_size,
                              hipStream_t stream) {
    const int* seq = (const int*)d_in[0];
    const int* slen = (const int*)d_in[1];
    const float* emb = (const float*)d_in[2];
    const float* lin = (const float*)d_in[3];
    const float* wq = (const float*)d_in[4];
    const float* wk = (const float*)d_in[5];
    float* out = (float*)d_out;
    float* ws = (float*)d_ws;

    float* qpre  = ws;                         // [l][b][d] fp32 = 327680 floats
    float* Upart = ws + 327680;                // [h][p][d'][e] fp32 = 524288
    unsigned short* ql_bf = (unsigned short*)(ws + 851968);   // [l][b][e] = 327680 us
    unsigned short* Qt_bf = (unsigned short*)(ws + 1015808);  // [m][b][d] = 1310720 us
    // ends at float offset 1671168 = 6.7 MB

    k_qpre<<<dim3(BB), dim3(256), 0, stream>>>(seq, slen, emb, qpre);
    k_wu2<<<dim3(208), dim3(256), 0, stream>>>(wq, wk, qpre, lin, Upart, ql_bf);
    k_qt<<<dim3(160), dim3(256), 0, stream>>>(ql_bf, Upart, Qt_bf);
    k_attn_out<<<dim3(BB), dim3(1024), 0, stream>>>(seq, emb, Qt_bf, out);
}

// Round 18
// 36.227 us; speedup vs baseline: 2.2890x; 1.2386x over previous
//
#include <hip/hip_runtime.h>
#include <hip/hip_bf16.h>

// AttentionMixerRec: B=256 S=200 D=256 V=100000 L=5 H=4
// scores[b,h,l,s] = (ql[b,l] @ U[h]) . emb[b,s] / 16
//   U[h][e][d'] = sum_f WQ[h][f][e] WK[h][f][d'];  ql = qpre @ lin^T;
//   qpre[b,l] = sum of emb rows s in [max(len-1-l,0), len-1].
// v18: v17 (44.9us) with the whole GEMM chain on MFMA:
//     (a) U tiles = bf16 MFMA (transpose-staged WQ/WK slabs), writing UT_bf
//         [d'][e] directly -- K-split + fp32 Upart machinery deleted;
//     (b) ql tiles = bf16 MFMA (v14's wiring, operands k-contiguous);
//     (c) k_qt B-staging = plain bf16 copy (32KB vs 128KB/block).
//     Pre-commit: absmax > 1.2e-4 -> revert U to fp32. attn/qpre = v17.

#define DD 256
#define SS 200
#define BB 256
#define LL 5
#define HH 4
#define NC 20   // H*L
#define P_ER 264   // er pitch in halves
#define P_BF 264   // bf16 slab pitch (16B-aligned rows)
#define P_E  260   // e overlay pitch in floats

typedef __attribute__((ext_vector_type(8))) short bf16x8;
typedef __attribute__((ext_vector_type(4))) float f32x4;

__device__ __forceinline__ unsigned short f2bf(float f) {
    __hip_bfloat16 h = __float2bfloat16(f);
    union { __hip_bfloat16 b; unsigned short u; } c; c.b = h; return c.u;
}
__device__ __forceinline__ float bf2f(unsigned short u) {
    union { unsigned i; float f; } c; c.i = (unsigned)u << 16; return c.f;
}

// ---- k_qpre: suffix gather, 5 rows in flight (256 blocks) ----
__global__ __launch_bounds__(256) void k_qpre(const int* __restrict__ seq,
                                              const int* __restrict__ slen,
                                              const float* __restrict__ emb,
                                              float* __restrict__ qpre) {
    __shared__ int rows[256];
    int b = blockIdx.x, t = threadIdx.x;
    rows[t] = (t < SS) ? seq[b * SS + t] : 0;
    __syncthreads();
    int len = slen[b];
    int p[LL];
    #pragma unroll
    for (int l = 0; l < LL; ++l) p[l] = max(len - 1 - l, 0);
    float v[LL];
    #pragma unroll
    for (int l = 0; l < LL; ++l)
        v[l] = emb[(size_t)rows[p[l]] * DD + t];
    float acc = v[0];
    qpre[(size_t)b * DD + t] = acc;
    #pragma unroll
    for (int l = 1; l < LL; ++l) {
        if (p[l] != p[l - 1]) acc += v[l];
        qpre[(size_t)(l * BB + b) * DD + t] = acc;
    }
}

// ---- k_wu: blocks 0..63 = U MFMA tiles -> UT_bf; 64..143 = ql MFMA tiles ----
__global__ __launch_bounds__(256) void k_wu(const float* __restrict__ wq,
                                            const float* __restrict__ wk,
                                            const float* __restrict__ qpre,
                                            const float* __restrict__ lin,
                                            unsigned short* __restrict__ UT_bf,
                                            unsigned short* __restrict__ ql_bf) {
    __shared__ unsigned short SA[64 * P_BF];
    __shared__ unsigned short SBL[64 * P_BF];
    int blk = blockIdx.x, t = threadIdx.x;
    int lane = t & 63, w = t >> 6;
    int fr = lane & 15, ko = (lane >> 4) * 8;
    int crow = (lane >> 4) * 4, ccol = lane & 15;

    if (blk < 64) {
        // ---- U tile: U[e][d'] = sum_f WQ[f][e] WK[f][d'] over tile i0(e),j0(d') ----
        int h = blk >> 4, tile = blk & 15;
        int i0 = (tile >> 2) * 64, j0 = (tile & 3) * 64;
        const float* GQ = wq + (size_t)h * 65536;
        const float* GK = wk + (size_t)h * 65536;
        // transpose-stage: SA[e_local][f] = WQ[f][i0+e], SBL[d_local][f] = WK[f][j0+d]
        int ib = (lane & 15) * 4;
        for (int it = 0; it < 16; ++it) {
            int k = it * 16 + w * 4 + (lane >> 4);
            float4 a = *(const float4*)&GQ[(size_t)k * DD + i0 + ib];
            SA[(ib + 0) * P_BF + k] = f2bf(a.x);
            SA[(ib + 1) * P_BF + k] = f2bf(a.y);
            SA[(ib + 2) * P_BF + k] = f2bf(a.z);
            SA[(ib + 3) * P_BF + k] = f2bf(a.w);
            float4 bv = *(const float4*)&GK[(size_t)k * DD + j0 + ib];
            SBL[(ib + 0) * P_BF + k] = f2bf(bv.x);
            SBL[(ib + 1) * P_BF + k] = f2bf(bv.y);
            SBL[(ib + 2) * P_BF + k] = f2bf(bv.z);
            SBL[(ib + 3) * P_BF + k] = f2bf(bv.w);
        }
        __syncthreads();
        f32x4 acc[4] = {{0.f,0.f,0.f,0.f},{0.f,0.f,0.f,0.f},
                        {0.f,0.f,0.f,0.f},{0.f,0.f,0.f,0.f}};
        for (int kk = 0; kk < 8; ++kk) {
            int kb = kk * 32 + ko;
            bf16x8 a = *(const bf16x8*)&SA[(w * 16 + fr) * P_BF + kb];
            #pragma unroll
            for (int q = 0; q < 4; ++q) {
                bf16x8 bq = *(const bf16x8*)&SBL[(q * 16 + fr) * P_BF + kb];
                acc[q] = __builtin_amdgcn_mfma_f32_16x16x32_bf16(a, bq, acc[q], 0, 0, 0);
            }
        }
        // D: row(e) = w*16+crow+jj, col(d') = q*16+ccol; write UT_bf[h][d'][e]
        #pragma unroll
        for (int q = 0; q < 4; ++q) {
            ushort4 o;
            o.x = f2bf(acc[q][0]); o.y = f2bf(acc[q][1]);
            o.z = f2bf(acc[q][2]); o.w = f2bf(acc[q][3]);
            *(ushort4*)&UT_bf[((size_t)h * 256 + j0 + q * 16 + ccol) * DD
                              + i0 + w * 16 + crow] = o;
        }
    } else {
        // ---- ql tile: ql[b][e] = sum_d qpre[l][b][d] lin[l][e][d] ----
        int z = blk - 64;
        int l = z >> 4, tile = z & 15;
        int b0 = (tile >> 2) * 64, e0 = (tile & 3) * 64;
        for (int rr = w; rr < 64; rr += 4) {
            float4 a = *(const float4*)&qpre[((size_t)l * 256 + b0 + rr) * DD + lane * 4];
            ushort4 oa;
            oa.x = f2bf(a.x); oa.y = f2bf(a.y); oa.z = f2bf(a.z); oa.w = f2bf(a.w);
            *(ushort4*)&SA[rr * P_BF + lane * 4] = oa;
            float4 bv = *(const float4*)&lin[(size_t)l * 65536 + (size_t)(e0 + rr) * DD + lane * 4];
            ushort4 ob;
            ob.x = f2bf(bv.x); ob.y = f2bf(bv.y); ob.z = f2bf(bv.z); ob.w = f2bf(bv.w);
            *(ushort4*)&SBL[rr * P_BF + lane * 4] = ob;
        }
        __syncthreads();
        f32x4 acc[4] = {{0.f,0.f,0.f,0.f},{0.f,0.f,0.f,0.f},
                        {0.f,0.f,0.f,0.f},{0.f,0.f,0.f,0.f}};
        for (int kk = 0; kk < 8; ++kk) {
            int kb = kk * 32 + ko;
            bf16x8 a = *(const bf16x8*)&SA[(w * 16 + fr) * P_BF + kb];
            #pragma unroll
            for (int q = 0; q < 4; ++q) {
                bf16x8 bq = *(const bf16x8*)&SBL[(q * 16 + fr) * P_BF + kb];
                acc[q] = __builtin_amdgcn_mfma_f32_16x16x32_bf16(a, bq, acc[q], 0, 0, 0);
            }
        }
        // D: row(b) = w*16+crow+jj, col(e) = q*16+ccol; write ql_bf[l][b][e]
        #pragma unroll
        for (int q = 0; q < 4; ++q)
            #pragma unroll
            for (int j = 0; j < 4; ++j)
                ql_bf[((size_t)l * 256 + b0 + w * 16 + crow + j) * DD
                      + e0 + q * 16 + ccol] = f2bf(acc[q][j]);
    }
}

// ---- k_qt: Qt_bf[z=h*5+l][b][d'] via bf16 MFMA, tile 128x64, 160 blocks ----
__global__ __launch_bounds__(256) void k_qt(const unsigned short* __restrict__ ql_bf,
                                            const unsigned short* __restrict__ UT_bf,
                                            unsigned short* __restrict__ Qt_bf) {
    __shared__ unsigned short Asl[128 * P_BF];
    __shared__ unsigned short Bsl[64 * P_BF];
    int blk = blockIdx.x;
    int z = blk >> 3, sub = blk & 7;
    int h = z / 5, l = z % 5;
    int b0 = (sub >> 2) * 128, d0 = (sub & 3) * 64;
    int t = threadIdx.x, lane = t & 63, w = t >> 6;

    const unsigned short* gA = ql_bf + ((size_t)l * 256 + b0) * DD;
    #pragma unroll
    for (int r = 0; r < 16; ++r) {
        int c = r * 256 + t;
        int row = c >> 5, kc = c & 31;
        *(uint4*)&Asl[row * P_BF + kc * 8] = *(const uint4*)&gA[(size_t)row * DD + kc * 8];
    }
    const unsigned short* gB = UT_bf + ((size_t)h * 256 + d0) * DD;
    #pragma unroll
    for (int r = 0; r < 8; ++r) {
        int c = r * 256 + t;
        int row = c >> 5, kc = c & 31;
        *(uint4*)&Bsl[row * P_BF + kc * 8] = *(const uint4*)&gB[(size_t)row * DD + kc * 8];
    }
    __syncthreads();

    f32x4 zero = {0.f, 0.f, 0.f, 0.f};
    f32x4 acc[2][4];
    #pragma unroll
    for (int p = 0; p < 2; ++p)
        #pragma unroll
        for (int q = 0; q < 4; ++q) acc[p][q] = zero;

    int ar = w * 32 + (lane & 15);
    int br = lane & 15;
    int ko = (lane >> 4) * 8;
    for (int kk = 0; kk < 8; ++kk) {
        int kb = kk * 32 + ko;
        bf16x8 a0 = *(const bf16x8*)&Asl[(size_t)ar * P_BF + kb];
        bf16x8 a1 = *(const bf16x8*)&Asl[(size_t)(ar + 16) * P_BF + kb];
        bf16x8 b0 = *(const bf16x8*)&Bsl[(size_t)br * P_BF + kb];
        bf16x8 b1 = *(const bf16x8*)&Bsl[(size_t)(br + 16) * P_BF + kb];
        bf16x8 b2 = *(const bf16x8*)&Bsl[(size_t)(br + 32) * P_BF + kb];
        bf16x8 b3 = *(const bf16x8*)&Bsl[(size_t)(br + 48) * P_BF + kb];
        acc[0][0] = __builtin_amdgcn_mfma_f32_16x16x32_bf16(a0, b0, acc[0][0], 0, 0, 0);
        acc[0][1] = __builtin_amdgcn_mfma_f32_16x16x32_bf16(a0, b1, acc[0][1], 0, 0, 0);
        acc[0][2] = __builtin_amdgcn_mfma_f32_16x16x32_bf16(a0, b2, acc[0][2], 0, 0, 0);
        acc[0][3] = __builtin_amdgcn_mfma_f32_16x16x32_bf16(a0, b3, acc[0][3], 0, 0, 0);
        acc[1][0] = __builtin_amdgcn_mfma_f32_16x16x32_bf16(a1, b0, acc[1][0], 0, 0, 0);
        acc[1][1] = __builtin_amdgcn_mfma_f32_16x16x32_bf16(a1, b1, acc[1][1], 0, 0, 0);
        acc[1][2] = __builtin_amdgcn_mfma_f32_16x16x32_bf16(a1, b2, acc[1][2], 0, 0, 0);
        acc[1][3] = __builtin_amdgcn_mfma_f32_16x16x32_bf16(a1, b3, acc[1][3], 0, 0, 0);
    }

    int crow = (lane >> 4) * 4, ccol = lane & 15;
    unsigned short* Qb = Qt_bf + (size_t)z * 65536;
    #pragma unroll
    for (int p = 0; p < 2; ++p)
        #pragma unroll
        for (int q = 0; q < 4; ++q)
            #pragma unroll
            for (int j = 0; j < 4; ++j) {
                int row = b0 + w * 32 + p * 16 + crow + j;
                int col = d0 + q * 16 + ccol;
                Qb[(size_t)row * DD + col] = f2bf(acc[p][q][j]);
            }
}

// ---- fused attention (v17 verbatim); phase A = bf16 MFMA; phase C from LDS ----
__global__ __launch_bounds__(1024, 4) void k_attn_out(const int* __restrict__ seq,
                                                      const float* __restrict__ emb,
                                                      const unsigned short* __restrict__ Qt_bf,
                                                      float* __restrict__ out) {
    __shared__ float smem[38016];
    __shared__ float ssum[NC];
    __shared__ int rowsl[256];
    unsigned short* qtb = (unsigned short*)smem;            // [32][P_BF]
    unsigned short* er  = (unsigned short*)(smem + 4224);   // [256][P_ER]
    float* e      = smem + 30624;          // rows 200.. overlay, pitch P_E
    float* pooled = smem + 35824;
    float* par    = smem + 36080;

    int b = blockIdx.x, t = threadIdx.x;
    int lane = t & 63, wave = t >> 6;

    if (t < 256) rowsl[t] = (t < SS) ? seq[b * SS + t] : 0;
    __syncthreads();

    for (int r = wave; r < 32; r += 16) {
        if (r < NC) {
            uint2 v = *(const uint2*)&Qt_bf[((size_t)r * BB + b) * DD + lane * 4];
            *(uint2*)&qtb[r * P_BF + lane * 4] = v;
        } else {
            *(uint2*)&qtb[r * P_BF + lane * 4] = make_uint2(0u, 0u);
        }
    }
    #pragma unroll
    for (int k = 0; k < 16; ++k) {
        int r = wave + k * 16;
        if (r < SS) {
            int row = __builtin_amdgcn_readfirstlane(rowsl[r]);
            float4 v = *(const float4*)&emb[(size_t)row * DD + lane * 4];
            ushort4 o;
            o.x = f2bf(v.x); o.y = f2bf(v.y); o.z = f2bf(v.z); o.w = f2bf(v.w);
            *(ushort4*)&er[r * P_ER + lane * 4] = o;
        } else {
            ushort4 zz = {0, 0, 0, 0};
            *(ushort4*)&er[r * P_ER + lane * 4] = zz;
        }
    }
    __syncthreads();

    int fr = lane & 15, ko = (lane >> 4) * 8;
    int crow = (lane >> 4) * 4, ccol = lane & 15;
    f32x4 zero4 = {0.f, 0.f, 0.f, 0.f};
    f32x4 acc0 = zero4, acc1 = zero4;
    const unsigned short* erb = er + (wave * 16 + fr) * P_ER;
    #pragma unroll
    for (int kk = 0; kk < 8; ++kk) {
        int kb = kk * 32 + ko;
        bf16x8 bv = *(const bf16x8*)&erb[kb];
        bf16x8 a0 = *(const bf16x8*)&qtb[fr * P_BF + kb];
        bf16x8 a1 = *(const bf16x8*)&qtb[(16 + fr) * P_BF + kb];
        acc0 = __builtin_amdgcn_mfma_f32_16x16x32_bf16(a0, bv, acc0, 0, 0, 0);
        acc1 = __builtin_amdgcn_mfma_f32_16x16x32_bf16(a1, bv, acc1, 0, 0, 0);
    }
    __syncthreads();

    int s = wave * 16 + ccol;
    bool sv = (s < SS);
    #pragma unroll
    for (int j = 0; j < 4; ++j) {
        int m0 = crow + j;
        e[m0 * P_E + s] = sv ? __expf(acc0[j] * 0.0625f) : 0.f;
    }
    if (crow == 0) {
        #pragma unroll
        for (int j = 0; j < 4; ++j)
            e[(16 + j) * P_E + s] = sv ? __expf(acc1[j] * 0.0625f) : 0.f;
    }
    __syncthreads();

    for (int m = wave; m < NC; m += 16) {
        float v = e[m * P_E + lane] + e[m * P_E + lane + 64] +
                  e[m * P_E + lane + 128] + e[m * P_E + lane + 192];
        #pragma unroll
        for (int off = 32; off >= 1; off >>= 1) v += __shfl_xor(v, off);
        if (lane == 0) ssum[m] = __frcp_rn(v);
    }
    __syncthreads();

    if (t < 256) {
        float r = 0.f;
        #pragma unroll
        for (int h = 0; h < HH; ++h) {
            float p4 = 0.f;
            #pragma unroll
            for (int l = 0; l < LL; ++l) {
                int m = h * LL + l;
                float a = e[m * P_E + t] * ssum[m];
                float a2 = a * a;
                p4 += a2 * a2;
            }
            r += sqrtf(sqrtf(p4));
        }
        pooled[t] = 0.25f * r;
    }
    __syncthreads();

    int d = t & 255, sq = t >> 8;
    int sbase = sq * 50;
    float o = 0.f;
    #pragma unroll 10
    for (int i = 0; i < 50; ++i) {
        int s2 = sbase + i;
        o = fmaf(pooled[s2], bf2f(er[s2 * P_ER + d]), o);
    }
    par[sq * 256 + d] = o;
    __syncthreads();
    if (t < 256) out[(size_t)b * DD + t] =
        par[t] + par[256 + t] + par[512 + t] + par[768 + t];
}

extern "C" void kernel_launch(void* const* d_in, const int* in_sizes, int n_in,
                              void* d_out, int out_size, void* d_ws, size_t ws_size,
                              hipStream_t stream) {
    const int* seq = (const int*)d_in[0];
    const int* slen = (const int*)d_in[1];
    const float* emb = (const float*)d_in[2];
    const float* lin = (const float*)d_in[3];
    const float* wq = (const float*)d_in[4];
    const float* wk = (const float*)d_in[5];
    float* out = (float*)d_out;
    float* ws = (float*)d_ws;

    float* qpre = ws;                                        // [l][b][d] fp32 = 327680 f
    unsigned short* UT_bf = (unsigned short*)(ws + 327680);  // [h][d'][e] = 262144 us
    unsigned short* ql_bf = (unsigned short*)(ws + 458752);  // [l][b][e] = 327680 us
    unsigned short* Qt_bf = (unsigned short*)(ws + 622592);  // [m][b][d] = 1310720 us
    // ends at float offset 1277952 = 5.1 MB

    k_qpre<<<dim3(BB), dim3(256), 0, stream>>>(seq, slen, emb, qpre);
    k_wu<<<dim3(144), dim3(256), 0, stream>>>(wq, wk, qpre, lin, UT_bf, ql_bf);
    k_qt<<<dim3(160), dim3(256), 0, stream>>>(ql_bf, UT_bf, Qt_bf);
    k_attn_out<<<dim3(BB), dim3(1024), 0, stream>>>(seq, emb, Qt_bf, out);
}

// Round 19
// 35.709 us; speedup vs baseline: 2.3222x; 1.0145x over previous
//
#include <hip/hip_runtime.h>
#include <hip/hip_bf16.h>

// AttentionMixerRec: B=256 S=200 D=256 V=100000 L=5 H=4
// scores[b,h,l,s] = (ql[b,l] @ U[h]) . emb[b,s] / 16
//   U[h][e][d'] = sum_f WQ[h][f][e] WK[h][f][d'];  ql = qpre @ lin^T;
//   qpre[b,l] = sum of emb rows s in [max(len-1-l,0), len-1].
// v19: v18 (36.2us) micro-shaves: (a) qpre stored bf16 (sole consumer
//     bf16-converts anyway -- conversion moved to producer, bit-identical;
//     halves that read + removes converts); (b) attn p4-pooling spread over
//     all 1024 threads ((s,h) pairs -> par[h][s], then 256-thread combine).
//     4-launch DAG is the proven floor ({U,qpre} -> ql -> Qt -> attn; device
//     sync and all fusion variants measured worse). Rest = v18 verbatim.

#define DD 256
#define SS 200
#define BB 256
#define LL 5
#define HH 4
#define NC 20   // H*L
#define P_ER 264   // er pitch in halves
#define P_BF 264   // bf16 slab pitch (16B-aligned rows)
#define P_E  260   // e overlay pitch in floats

typedef __attribute__((ext_vector_type(8))) short bf16x8;
typedef __attribute__((ext_vector_type(4))) float f32x4;

__device__ __forceinline__ unsigned short f2bf(float f) {
    __hip_bfloat16 h = __float2bfloat16(f);
    union { __hip_bfloat16 b; unsigned short u; } c; c.b = h; return c.u;
}
__device__ __forceinline__ float bf2f(unsigned short u) {
    union { unsigned i; float f; } c; c.i = (unsigned)u << 16; return c.f;
}

// ---- k_qpre: suffix gather, 5 rows in flight; bf16 output (256 blocks) ----
__global__ __launch_bounds__(256) void k_qpre(const int* __restrict__ seq,
                                              const int* __restrict__ slen,
                                              const float* __restrict__ emb,
                                              unsigned short* __restrict__ qpre_bf) {
    __shared__ int rows[256];
    int b = blockIdx.x, t = threadIdx.x;
    rows[t] = (t < SS) ? seq[b * SS + t] : 0;
    __syncthreads();
    int len = slen[b];
    int p[LL];
    #pragma unroll
    for (int l = 0; l < LL; ++l) p[l] = max(len - 1 - l, 0);
    float v[LL];
    #pragma unroll
    for (int l = 0; l < LL; ++l)
        v[l] = emb[(size_t)rows[p[l]] * DD + t];
    float acc = v[0];
    qpre_bf[(size_t)b * DD + t] = f2bf(acc);
    #pragma unroll
    for (int l = 1; l < LL; ++l) {
        if (p[l] != p[l - 1]) acc += v[l];
        qpre_bf[(size_t)(l * BB + b) * DD + t] = f2bf(acc);
    }
}

// ---- k_wu: blocks 0..63 = U MFMA tiles -> UT_bf; 64..143 = ql MFMA tiles ----
__global__ __launch_bounds__(256) void k_wu(const float* __restrict__ wq,
                                            const float* __restrict__ wk,
                                            const unsigned short* __restrict__ qpre_bf,
                                            const float* __restrict__ lin,
                                            unsigned short* __restrict__ UT_bf,
                                            unsigned short* __restrict__ ql_bf) {
    __shared__ unsigned short SA[64 * P_BF];
    __shared__ unsigned short SBL[64 * P_BF];
    int blk = blockIdx.x, t = threadIdx.x;
    int lane = t & 63, w = t >> 6;
    int fr = lane & 15, ko = (lane >> 4) * 8;
    int crow = (lane >> 4) * 4, ccol = lane & 15;

    if (blk < 64) {
        // ---- U tile: U[e][d'] = sum_f WQ[f][e] WK[f][d'] ----
        int h = blk >> 4, tile = blk & 15;
        int i0 = (tile >> 2) * 64, j0 = (tile & 3) * 64;
        const float* GQ = wq + (size_t)h * 65536;
        const float* GK = wk + (size_t)h * 65536;
        int ib = (lane & 15) * 4;
        for (int it = 0; it < 16; ++it) {
            int k = it * 16 + w * 4 + (lane >> 4);
            float4 a = *(const float4*)&GQ[(size_t)k * DD + i0 + ib];
            SA[(ib + 0) * P_BF + k] = f2bf(a.x);
            SA[(ib + 1) * P_BF + k] = f2bf(a.y);
            SA[(ib + 2) * P_BF + k] = f2bf(a.z);
            SA[(ib + 3) * P_BF + k] = f2bf(a.w);
            float4 bv = *(const float4*)&GK[(size_t)k * DD + j0 + ib];
            SBL[(ib + 0) * P_BF + k] = f2bf(bv.x);
            SBL[(ib + 1) * P_BF + k] = f2bf(bv.y);
            SBL[(ib + 2) * P_BF + k] = f2bf(bv.z);
            SBL[(ib + 3) * P_BF + k] = f2bf(bv.w);
        }
        __syncthreads();
        f32x4 acc[4] = {{0.f,0.f,0.f,0.f},{0.f,0.f,0.f,0.f},
                        {0.f,0.f,0.f,0.f},{0.f,0.f,0.f,0.f}};
        for (int kk = 0; kk < 8; ++kk) {
            int kb = kk * 32 + ko;
            bf16x8 a = *(const bf16x8*)&SA[(w * 16 + fr) * P_BF + kb];
            #pragma unroll
            for (int q = 0; q < 4; ++q) {
                bf16x8 bq = *(const bf16x8*)&SBL[(q * 16 + fr) * P_BF + kb];
                acc[q] = __builtin_amdgcn_mfma_f32_16x16x32_bf16(a, bq, acc[q], 0, 0, 0);
            }
        }
        #pragma unroll
        for (int q = 0; q < 4; ++q) {
            ushort4 o;
            o.x = f2bf(acc[q][0]); o.y = f2bf(acc[q][1]);
            o.z = f2bf(acc[q][2]); o.w = f2bf(acc[q][3]);
            *(ushort4*)&UT_bf[((size_t)h * 256 + j0 + q * 16 + ccol) * DD
                              + i0 + w * 16 + crow] = o;
        }
    } else {
        // ---- ql tile: ql[b][e] = sum_d qpre[l][b][d] lin[l][e][d] ----
        int z = blk - 64;
        int l = z >> 4, tile = z & 15;
        int b0 = (tile >> 2) * 64, e0 = (tile & 3) * 64;
        for (int rr = w; rr < 64; rr += 4) {
            uint2 a = *(const uint2*)&qpre_bf[((size_t)l * 256 + b0 + rr) * DD + lane * 4];
            *(uint2*)&SA[rr * P_BF + lane * 4] = a;
            float4 bv = *(const float4*)&lin[(size_t)l * 65536 + (size_t)(e0 + rr) * DD + lane * 4];
            ushort4 ob;
            ob.x = f2bf(bv.x); ob.y = f2bf(bv.y); ob.z = f2bf(bv.z); ob.w = f2bf(bv.w);
            *(ushort4*)&SBL[rr * P_BF + lane * 4] = ob;
        }
        __syncthreads();
        f32x4 acc[4] = {{0.f,0.f,0.f,0.f},{0.f,0.f,0.f,0.f},
                        {0.f,0.f,0.f,0.f},{0.f,0.f,0.f,0.f}};
        for (int kk = 0; kk < 8; ++kk) {
            int kb = kk * 32 + ko;
            bf16x8 a = *(const bf16x8*)&SA[(w * 16 + fr) * P_BF + kb];
            #pragma unroll
            for (int q = 0; q < 4; ++q) {
                bf16x8 bq = *(const bf16x8*)&SBL[(q * 16 + fr) * P_BF + kb];
                acc[q] = __builtin_amdgcn_mfma_f32_16x16x32_bf16(a, bq, acc[q], 0, 0, 0);
            }
        }
        #pragma unroll
        for (int q = 0; q < 4; ++q)
            #pragma unroll
            for (int j = 0; j < 4; ++j)
                ql_bf[((size_t)l * 256 + b0 + w * 16 + crow + j) * DD
                      + e0 + q * 16 + ccol] = f2bf(acc[q][j]);
    }
}

// ---- k_qt: Qt_bf[z=h*5+l][b][d'] via bf16 MFMA, tile 128x64, 160 blocks ----
__global__ __launch_bounds__(256) void k_qt(const unsigned short* __restrict__ ql_bf,
                                            const unsigned short* __restrict__ UT_bf,
                                            unsigned short* __restrict__ Qt_bf) {
    __shared__ unsigned short Asl[128 * P_BF];
    __shared__ unsigned short Bsl[64 * P_BF];
    int blk = blockIdx.x;
    int z = blk >> 3, sub = blk & 7;
    int h = z / 5, l = z % 5;
    int b0 = (sub >> 2) * 128, d0 = (sub & 3) * 64;
    int t = threadIdx.x, lane = t & 63, w = t >> 6;

    const unsigned short* gA = ql_bf + ((size_t)l * 256 + b0) * DD;
    #pragma unroll
    for (int r = 0; r < 16; ++r) {
        int c = r * 256 + t;
        int row = c >> 5, kc = c & 31;
        *(uint4*)&Asl[row * P_BF + kc * 8] = *(const uint4*)&gA[(size_t)row * DD + kc * 8];
    }
    const unsigned short* gB = UT_bf + ((size_t)h * 256 + d0) * DD;
    #pragma unroll
    for (int r = 0; r < 8; ++r) {
        int c = r * 256 + t;
        int row = c >> 5, kc = c & 31;
        *(uint4*)&Bsl[row * P_BF + kc * 8] = *(const uint4*)&gB[(size_t)row * DD + kc * 8];
    }
    __syncthreads();

    f32x4 zero = {0.f, 0.f, 0.f, 0.f};
    f32x4 acc[2][4];
    #pragma unroll
    for (int p = 0; p < 2; ++p)
        #pragma unroll
        for (int q = 0; q < 4; ++q) acc[p][q] = zero;

    int ar = w * 32 + (lane & 15);
    int br = lane & 15;
    int ko = (lane >> 4) * 8;
    for (int kk = 0; kk < 8; ++kk) {
        int kb = kk * 32 + ko;
        bf16x8 a0 = *(const bf16x8*)&Asl[(size_t)ar * P_BF + kb];
        bf16x8 a1 = *(const bf16x8*)&Asl[(size_t)(ar + 16) * P_BF + kb];
        bf16x8 b0 = *(const bf16x8*)&Bsl[(size_t)br * P_BF + kb];
        bf16x8 b1 = *(const bf16x8*)&Bsl[(size_t)(br + 16) * P_BF + kb];
        bf16x8 b2 = *(const bf16x8*)&Bsl[(size_t)(br + 32) * P_BF + kb];
        bf16x8 b3 = *(const bf16x8*)&Bsl[(size_t)(br + 48) * P_BF + kb];
        acc[0][0] = __builtin_amdgcn_mfma_f32_16x16x32_bf16(a0, b0, acc[0][0], 0, 0, 0);
        acc[0][1] = __builtin_amdgcn_mfma_f32_16x16x32_bf16(a0, b1, acc[0][1], 0, 0, 0);
        acc[0][2] = __builtin_amdgcn_mfma_f32_16x16x32_bf16(a0, b2, acc[0][2], 0, 0, 0);
        acc[0][3] = __builtin_amdgcn_mfma_f32_16x16x32_bf16(a0, b3, acc[0][3], 0, 0, 0);
        acc[1][0] = __builtin_amdgcn_mfma_f32_16x16x32_bf16(a1, b0, acc[1][0], 0, 0, 0);
        acc[1][1] = __builtin_amdgcn_mfma_f32_16x16x32_bf16(a1, b1, acc[1][1], 0, 0, 0);
        acc[1][2] = __builtin_amdgcn_mfma_f32_16x16x32_bf16(a1, b2, acc[1][2], 0, 0, 0);
        acc[1][3] = __builtin_amdgcn_mfma_f32_16x16x32_bf16(a1, b3, acc[1][3], 0, 0, 0);
    }

    int crow = (lane >> 4) * 4, ccol = lane & 15;
    unsigned short* Qb = Qt_bf + (size_t)z * 65536;
    #pragma unroll
    for (int p = 0; p < 2; ++p)
        #pragma unroll
        for (int q = 0; q < 4; ++q)
            #pragma unroll
            for (int j = 0; j < 4; ++j) {
                int row = b0 + w * 32 + p * 16 + crow + j;
                int col = d0 + q * 16 + ccol;
                Qb[(size_t)row * DD + col] = f2bf(acc[p][q][j]);
            }
}

// ---- fused attention; phase A = bf16 MFMA; phase C from LDS er ----
__global__ __launch_bounds__(1024, 4) void k_attn_out(const int* __restrict__ seq,
                                                      const float* __restrict__ emb,
                                                      const unsigned short* __restrict__ Qt_bf,
                                                      float* __restrict__ out) {
    __shared__ float smem[38016];
    __shared__ float ssum[NC];
    __shared__ int rowsl[256];
    unsigned short* qtb = (unsigned short*)smem;            // [32][P_BF]
    unsigned short* er  = (unsigned short*)(smem + 4224);   // [256][P_ER]
    float* e      = smem + 30624;          // rows 200.. overlay, pitch P_E
    float* pooled = smem + 35824;
    float* par    = smem + 36080;          // [4][256]

    int b = blockIdx.x, t = threadIdx.x;
    int lane = t & 63, wave = t >> 6;

    if (t < 256) rowsl[t] = (t < SS) ? seq[b * SS + t] : 0;
    __syncthreads();

    for (int r = wave; r < 32; r += 16) {
        if (r < NC) {
            uint2 v = *(const uint2*)&Qt_bf[((size_t)r * BB + b) * DD + lane * 4];
            *(uint2*)&qtb[r * P_BF + lane * 4] = v;
        } else {
            *(uint2*)&qtb[r * P_BF + lane * 4] = make_uint2(0u, 0u);
        }
    }
    #pragma unroll
    for (int k = 0; k < 16; ++k) {
        int r = wave + k * 16;
        if (r < SS) {
            int row = __builtin_amdgcn_readfirstlane(rowsl[r]);
            float4 v = *(const float4*)&emb[(size_t)row * DD + lane * 4];
            ushort4 o;
            o.x = f2bf(v.x); o.y = f2bf(v.y); o.z = f2bf(v.z); o.w = f2bf(v.w);
            *(ushort4*)&er[r * P_ER + lane * 4] = o;
        } else {
            ushort4 zz = {0, 0, 0, 0};
            *(ushort4*)&er[r * P_ER + lane * 4] = zz;
        }
    }
    __syncthreads();

    int fr = lane & 15, ko = (lane >> 4) * 8;
    int crow = (lane >> 4) * 4, ccol = lane & 15;
    f32x4 zero4 = {0.f, 0.f, 0.f, 0.f};
    f32x4 acc0 = zero4, acc1 = zero4;
    const unsigned short* erb = er + (wave * 16 + fr) * P_ER;
    #pragma unroll
    for (int kk = 0; kk < 8; ++kk) {
        int kb = kk * 32 + ko;
        bf16x8 bv = *(const bf16x8*)&erb[kb];
        bf16x8 a0 = *(const bf16x8*)&qtb[fr * P_BF + kb];
        bf16x8 a1 = *(const bf16x8*)&qtb[(16 + fr) * P_BF + kb];
        acc0 = __builtin_amdgcn_mfma_f32_16x16x32_bf16(a0, bv, acc0, 0, 0, 0);
        acc1 = __builtin_amdgcn_mfma_f32_16x16x32_bf16(a1, bv, acc1, 0, 0, 0);
    }
    __syncthreads();

    int s = wave * 16 + ccol;
    bool sv = (s < SS);
    #pragma unroll
    for (int j = 0; j < 4; ++j) {
        int m0 = crow + j;
        e[m0 * P_E + s] = sv ? __expf(acc0[j] * 0.0625f) : 0.f;
    }
    if (crow == 0) {
        #pragma unroll
        for (int j = 0; j < 4; ++j)
            e[(16 + j) * P_E + s] = sv ? __expf(acc1[j] * 0.0625f) : 0.f;
    }
    __syncthreads();

    for (int m = wave; m < NC; m += 16) {
        float v = e[m * P_E + lane] + e[m * P_E + lane + 64] +
                  e[m * P_E + lane + 128] + e[m * P_E + lane + 192];
        #pragma unroll
        for (int off = 32; off >= 1; off >>= 1) v += __shfl_xor(v, off);
        if (lane == 0) ssum[m] = __frcp_rn(v);
    }
    __syncthreads();

    // pooling over all 1024 threads: thread = (s = t&255, h = t>>8)
    {
        int s2 = t & 255, hh = t >> 8;
        float p4 = 0.f;
        #pragma unroll
        for (int l = 0; l < LL; ++l) {
            int m = hh * LL + l;
            float a = e[m * P_E + s2] * ssum[m];
            float a2 = a * a;
            p4 += a2 * a2;
        }
        par[hh * 256 + s2] = sqrtf(sqrtf(p4));
    }
    __syncthreads();
    if (t < 256)
        pooled[t] = 0.25f * (par[t] + par[256 + t] + par[512 + t] + par[768 + t]);
    __syncthreads();

    // phase C: out[b,d] = sum_s pooled[s] * er[s][d]  (LDS bf16, no global)
    int d = t & 255, sq = t >> 8;
    int sbase = sq * 50;
    float o = 0.f;
    #pragma unroll 10
    for (int i = 0; i < 50; ++i) {
        int s2 = sbase + i;
        o = fmaf(pooled[s2], bf2f(er[s2 * P_ER + d]), o);
    }
    par[sq * 256 + d] = o;
    __syncthreads();
    if (t < 256) out[(size_t)b * DD + t] =
        par[t] + par[256 + t] + par[512 + t] + par[768 + t];
}

extern "C" void kernel_launch(void* const* d_in, const int* in_sizes, int n_in,
                              void* d_out, int out_size, void* d_ws, size_t ws_size,
                              hipStream_t stream) {
    const int* seq = (const int*)d_in[0];
    const int* slen = (const int*)d_in[1];
    const float* emb = (const float*)d_in[2];
    const float* lin = (const float*)d_in[3];
    const float* wq = (const float*)d_in[4];
    const float* wk = (const float*)d_in[5];
    float* out = (float*)d_out;
    float* ws = (float*)d_ws;

    unsigned short* qpre_bf = (unsigned short*)ws;           // [l][b][d] = 327680 us
    unsigned short* UT_bf = (unsigned short*)(ws + 163840);  // [h][d'][e] = 262144 us
    unsigned short* ql_bf = (unsigned short*)(ws + 294912);  // [l][b][e] = 327680 us
    unsigned short* Qt_bf = (unsigned short*)(ws + 458752);  // [m][b][d] = 1310720 us
    // ends at float offset 1114112 = 4.5 MB

    k_qpre<<<dim3(BB), dim3(256), 0, stream>>>(seq, slen, emb, qpre_bf);
    k_wu<<<dim3(144), dim3(256), 0, stream>>>(wq, wk, qpre_bf, lin, UT_bf, ql_bf);
    k_qt<<<dim3(160), dim3(256), 0, stream>>>(ql_bf, UT_bf, Qt_bf);
    k_attn_out<<<dim3(BB), dim3(1024), 0, stream>>>(seq, emb, Qt_bf, out);
}